// Round 1
// baseline (21975.552 us; speedup 1.0000x reference)
//
#include <hip/hip_runtime.h>
#include <hip/hip_bf16.h>
#include <cmath>
#include <cstdint>

// ---------------------------------------------------------------------------
// CapsuleNet forward, fp32.
// Pipeline:
//   1. transpose_perm: conv weights (O,C,9,9) -> wT[k'][o], k' = (ky*9+kx)*CIN + c
//   2. conv_gemm (implicit GEMM, 128x64 tile, BK=16): conv1+ReLU -> h (chunked),
//      prim conv -> p[b][r][8] (capsule layout)
//   3. routing_kernel: one block per (class,b); priors kept virtual (5 streaming
//      passes over route_w from L2), logits/p in registers, -> caps (B,2,16)
//   4. mask_kernel: norms, class softmax, argmax mask -> classes (d_out), masked
//   5. dense_gemm x3: decoder with fused bias+ReLU/sigmoid -> d_out+2048
// ---------------------------------------------------------------------------

#define WS_WT1    0
#define N_WT1     62208       // 243*256
#define N_WTP     5308416     // 20736*256
#define N_P       9437184     // 1024*1152*8
#define N_CAPS    32768       // 1024*2*16
#define N_MASKED  32768       // 1024*32
#define N_D1      524288      // 1024*512
#define N_D2      1048576     // 1024*1024

// ------------------------- weight transpose (permuted) ----------------------
// in:  w[n][k], k = c*81 + khw   (N x K)
// out: wT[k'][n], k' = khw*CIN + c
template<int CIN>
__global__ void __launch_bounds__(256) transpose_perm(
    const float* __restrict__ w, float* __restrict__ wT, int N, int K)
{
    __shared__ float tile[64][65];
    const int k0 = blockIdx.x * 64, n0 = blockIdx.y * 64;
    const int t = threadIdx.x;
    const int kk = t & 63;
    for (int nn = t >> 6; nn < 64; nn += 4) {
        int n = n0 + nn, k = k0 + kk;
        tile[nn][kk] = (n < N && k < K) ? w[(size_t)n * K + k] : 0.f;
    }
    __syncthreads();
    const int nn = t & 63;
    for (int kk2 = t >> 6; kk2 < 64; kk2 += 4) {
        int n = n0 + nn, k = k0 + kk2;
        if (n < N && k < K) {
            int c = k / 81, khw = k % 81;
            wT[((size_t)khw * CIN + c) * N + n] = tile[nn][kk2];
        }
    }
}

// ------------------------- implicit-GEMM conv -------------------------------
// EPI 0: conv1 -> h[b_l][n][py*WOUT+px], bias+ReLU
// EPI 1: prim  -> p[(b_base+b_l)*1152 + (n>>3)*36 + pix][n&7], bias only
template<int CIN, int HIN, int WIN, int STRIDE, int HOUT, int WOUT, int KTOT, int EPI>
__global__ void __launch_bounds__(256) conv_gemm(
    const float* __restrict__ in, const float* __restrict__ wT,
    const float* __restrict__ bias, float* __restrict__ out, int b_base)
{
    __shared__ __align__(16) float As[16][128];
    __shared__ __align__(16) float Bs[16][64];
    __shared__ int otab[81];
    const int t  = threadIdx.x;
    const int m0 = blockIdx.x * 128;
    const int n0 = blockIdx.y * 64;

    if (t < 81) { int ky = t / 9, kx = t % 9; otab[t] = ky * WIN + kx; }

    // A staging coords (thread loads 8 k-rows of one m-column)
    const int m_l   = t & 127;
    const int k_off = (t >> 7) * 8;            // 0 or 8
    {
        // nothing
    }
    const int m  = m0 + m_l;
    const int bb = m / (HOUT * WOUT);
    const int pr = m % (HOUT * WOUT);
    const int py = pr / WOUT;
    const int px = pr % WOUT;
    const float* inb = in + (size_t)bb * CIN * HIN * WIN
                          + (size_t)(py * STRIDE) * WIN + (px * STRIDE);
    // B staging coords
    const int nb = (t & 15) * 4;
    const int kb = t >> 4;
    // micro-tile coords
    const int tx = t & 15, ty = t >> 4;

    float acc[8][4];
#pragma unroll
    for (int i = 0; i < 8; ++i)
#pragma unroll
        for (int j = 0; j < 4; ++j) acc[i][j] = 0.f;

    __syncthreads();   // otab ready

    for (int k0i = 0; k0i < KTOT; k0i += 16) {
        // stage A (im2col)
#pragma unroll
        for (int j = 0; j < 8; ++j) {
            int k = k0i + k_off + j;
            float v = 0.f;
            if (k < KTOT) {
                int khw = k / CIN;             // CIN=256 -> shift, CIN=3 -> magic
                int cc  = k - khw * CIN;
                v = inb[(size_t)cc * (HIN * WIN) + otab[khw]];
            }
            As[k_off + j][m_l] = v;
        }
        // stage B (weights, K-major)
        {
            int k = k0i + kb;
            float4 v4 = make_float4(0.f, 0.f, 0.f, 0.f);
            if (k < KTOT) v4 = *(const float4*)&wT[(size_t)k * 256 + n0 + nb];
            *(float4*)&Bs[kb][nb] = v4;
        }
        __syncthreads();
#pragma unroll
        for (int kk = 0; kk < 16; ++kk) {
            float4 a0 = *(const float4*)&As[kk][ty * 8];
            float4 a1 = *(const float4*)&As[kk][ty * 8 + 4];
            float4 b0 = *(const float4*)&Bs[kk][tx * 4];
            float av[8] = {a0.x, a0.y, a0.z, a0.w, a1.x, a1.y, a1.z, a1.w};
            float bv[4] = {b0.x, b0.y, b0.z, b0.w};
#pragma unroll
            for (int i = 0; i < 8; ++i)
#pragma unroll
                for (int j = 0; j < 4; ++j)
                    acc[i][j] = fmaf(av[i], bv[j], acc[i][j]);
        }
        __syncthreads();
    }

    // epilogue
#pragma unroll
    for (int i = 0; i < 8; ++i) {
        int mm = m0 + ty * 8 + i;
        int bl = mm / (HOUT * WOUT);
        int pp = mm % (HOUT * WOUT);
#pragma unroll
        for (int j = 0; j < 4; ++j) {
            int n = n0 + tx * 4 + j;
            float v = acc[i][j] + bias[n];
            if (EPI == 0) {
                v = fmaxf(v, 0.f);
                out[((size_t)bl * 256 + n) * (HOUT * WOUT) + pp] = v;
            } else {
                int cap = n >> 3, vec = n & 7;
                int bg = b_base + bl;
                out[(((size_t)bg * 1152) + cap * 36 + pp) * 8 + vec] = v;
            }
        }
    }
}

// ------------------------- dynamic routing ----------------------------------
// grid (1024, 2): block per (b, c). 256 threads; r = t + 256*j (j<5).
__global__ void __launch_bounds__(256) routing_kernel(
    const float* __restrict__ p, const float* __restrict__ rw,
    float* __restrict__ caps)
{
    const int b = blockIdx.x;
    const int c = blockIdx.y;
    const int t = threadIdx.x;
    const int lane = t & 63, wid = t >> 6;
    __shared__ float redbuf[4];
    __shared__ float tred[4][16];
    __shared__ float outv[16];

    const float* pb  = p  + (size_t)b * 9216;
    const float* rwc = rw + (size_t)c * 147456;

    float p_loc[5][8];
    float l_loc[5];
#pragma unroll
    for (int j = 0; j < 5; ++j) {
        l_loc[j] = 0.f;
        int r = t + 256 * j;
        if (j < 4 || t < 128) {
            float4 v0 = *(const float4*)&pb[(size_t)r * 8];
            float4 v1 = *(const float4*)&pb[(size_t)r * 8 + 4];
            p_loc[j][0] = v0.x; p_loc[j][1] = v0.y; p_loc[j][2] = v0.z; p_loc[j][3] = v0.w;
            p_loc[j][4] = v1.x; p_loc[j][5] = v1.y; p_loc[j][6] = v1.z; p_loc[j][7] = v1.w;
        } else {
#pragma unroll
            for (int i = 0; i < 8; ++i) p_loc[j][i] = 0.f;
        }
    }

    for (int it = 0; it < 3; ++it) {
        // --- softmax over r (logits identical across v) ---
        float lm = -1e30f;
#pragma unroll
        for (int j = 0; j < 5; ++j) if (j < 4 || t < 128) lm = fmaxf(lm, l_loc[j]);
#pragma unroll
        for (int off = 32; off; off >>= 1) lm = fmaxf(lm, __shfl_down(lm, off, 64));
        __syncthreads();
        if (lane == 0) redbuf[wid] = lm;
        __syncthreads();
        lm = fmaxf(fmaxf(redbuf[0], redbuf[1]), fmaxf(redbuf[2], redbuf[3]));

        float e_loc[5];
        float ls = 0.f;
#pragma unroll
        for (int j = 0; j < 5; ++j) {
            e_loc[j] = 0.f;
            if (j < 4 || t < 128) { e_loc[j] = __expf(l_loc[j] - lm); ls += e_loc[j]; }
        }
#pragma unroll
        for (int off = 32; off; off >>= 1) ls += __shfl_down(ls, off, 64);
        __syncthreads();
        if (lane == 0) redbuf[wid] = ls;
        __syncthreads();
        ls = redbuf[0] + redbuf[1] + redbuf[2] + redbuf[3];
        const float inv = 1.f / ls;

        // --- pass A: t_v = inv * sum_r e_r * sum_i p[r][i]*W[r][i][v] ---
        float tv[16];
#pragma unroll
        for (int v = 0; v < 16; ++v) tv[v] = 0.f;
#pragma unroll
        for (int j = 0; j < 5; ++j) {
            if (j < 4 || t < 128) {
                int r = t + 256 * j;
                const float* wr = rwc + (size_t)r * 128;
#pragma unroll
                for (int i = 0; i < 8; ++i) {
                    float q = e_loc[j] * p_loc[j][i];
#pragma unroll
                    for (int v4 = 0; v4 < 4; ++v4) {
                        float4 w4 = *(const float4*)&wr[i * 16 + v4 * 4];
                        tv[v4 * 4 + 0] = fmaf(q, w4.x, tv[v4 * 4 + 0]);
                        tv[v4 * 4 + 1] = fmaf(q, w4.y, tv[v4 * 4 + 1]);
                        tv[v4 * 4 + 2] = fmaf(q, w4.z, tv[v4 * 4 + 2]);
                        tv[v4 * 4 + 3] = fmaf(q, w4.w, tv[v4 * 4 + 3]);
                    }
                }
            }
        }
#pragma unroll
        for (int v = 0; v < 16; ++v) {
            float xv = tv[v];
#pragma unroll
            for (int off = 32; off; off >>= 1) xv += __shfl_down(xv, off, 64);
            tv[v] = xv;
        }
        __syncthreads();
        if (lane == 0) {
#pragma unroll
            for (int v = 0; v < 16; ++v) tred[wid][v] = tv[v];
        }
        __syncthreads();
        if (t < 16) outv[t] = (tred[0][t] + tred[1][t] + tred[2][t] + tred[3][t]) * inv;
        __syncthreads();

        // --- squash ---
        float s2 = 0.f;
#pragma unroll
        for (int v = 0; v < 16; ++v) s2 += outv[v] * outv[v];
        const float scale = s2 / ((1.f + s2) * sqrtf(s2));

        if (it == 2) {
            if (t < 16) caps[((size_t)b * 2 + c) * 16 + t] = scale * outv[t];
        } else {
            float ov[16];
#pragma unroll
            for (int v = 0; v < 16; ++v) ov[v] = scale * outv[v];
            // --- pass B: logit[r] += sum_i p[r][i] * sum_v W[r][i][v]*out_v ---
#pragma unroll
            for (int j = 0; j < 5; ++j) {
                if (j < 4 || t < 128) {
                    int r = t + 256 * j;
                    const float* wr = rwc + (size_t)r * 128;
                    float d = 0.f;
#pragma unroll
                    for (int i = 0; i < 8; ++i) {
                        float u = 0.f;
#pragma unroll
                        for (int v4 = 0; v4 < 4; ++v4) {
                            float4 w4 = *(const float4*)&wr[i * 16 + v4 * 4];
                            u = fmaf(w4.x, ov[v4 * 4 + 0], u);
                            u = fmaf(w4.y, ov[v4 * 4 + 1], u);
                            u = fmaf(w4.z, ov[v4 * 4 + 2], u);
                            u = fmaf(w4.w, ov[v4 * 4 + 3], u);
                        }
                        d = fmaf(p_loc[j][i], u, d);
                    }
                    l_loc[j] += d;
                }
            }
            __syncthreads();
        }
    }
}

// ------------------------- class softmax + argmax mask ----------------------
__global__ void __launch_bounds__(256) mask_kernel(
    const float* __restrict__ caps, float* __restrict__ cls_out,
    float* __restrict__ masked)
{
    int b = blockIdx.x * 256 + threadIdx.x;
    if (b < 1024) {
        const float* cb = caps + (size_t)b * 32;
        float n0 = 0.f, n1 = 0.f;
#pragma unroll
        for (int v = 0; v < 16; ++v) {
            n0 = fmaf(cb[v], cb[v], n0);
            n1 = fmaf(cb[16 + v], cb[16 + v], n1);
        }
        n0 = sqrtf(n0); n1 = sqrtf(n1);
        float mx = fmaxf(n0, n1);
        float e0 = expf(n0 - mx), e1 = expf(n1 - mx);
        float inv = 1.f / (e0 + e1);
        cls_out[b * 2 + 0] = e0 * inv;
        cls_out[b * 2 + 1] = e1 * inv;
        int cs = (n1 > n0) ? 1 : 0;   // first-index-on-tie -> 0, matches argmax
#pragma unroll
        for (int v = 0; v < 16; ++v) {
            masked[(size_t)b * 32 + v]      = (cs == 0) ? cb[v] : 0.f;
            masked[(size_t)b * 32 + 16 + v] = (cs == 1) ? cb[16 + v] : 0.f;
        }
    }
}

// ------------------------- decoder GEMM -------------------------------------
// C[M,N] = act(A[M,K] @ Bw[K,N] + bias). ACT 0 = relu, 1 = sigmoid.
template<int ACT>
__global__ void __launch_bounds__(256) dense_gemm(
    const float* __restrict__ A, const float* __restrict__ Bw,
    const float* __restrict__ bias, float* __restrict__ out,
    int M, int N, int K)
{
    __shared__ __align__(16) float As[16][128];
    __shared__ __align__(16) float Bs[16][64];
    const int t  = threadIdx.x;
    const int m0 = blockIdx.x * 128, n0 = blockIdx.y * 64;
    const int tx = t & 15, ty = t >> 4;
    const int am = t >> 1;               // 0..127
    const int ak = (t & 1) * 8;          // 0 or 8
    const int nb = (t & 15) * 4, kb = t >> 4;

    float acc[8][4];
#pragma unroll
    for (int i = 0; i < 8; ++i)
#pragma unroll
        for (int j = 0; j < 4; ++j) acc[i][j] = 0.f;

    for (int k0i = 0; k0i < K; k0i += 16) {
        {
            const float* ap = A + (size_t)(m0 + am) * K + k0i + ak;
            float4 v0 = *(const float4*)ap;
            float4 v1 = *(const float4*)(ap + 4);
            As[ak + 0][am] = v0.x; As[ak + 1][am] = v0.y;
            As[ak + 2][am] = v0.z; As[ak + 3][am] = v0.w;
            As[ak + 4][am] = v1.x; As[ak + 5][am] = v1.y;
            As[ak + 6][am] = v1.z; As[ak + 7][am] = v1.w;
        }
        {
            int k = k0i + kb;
            int n = n0 + nb;
            float4 v4 = make_float4(0.f, 0.f, 0.f, 0.f);
            if (n + 3 < N) {
                v4 = *(const float4*)&Bw[(size_t)k * N + n];
            } else {
                float tmp[4] = {0.f, 0.f, 0.f, 0.f};
#pragma unroll
                for (int e = 0; e < 4; ++e)
                    if (n + e < N) tmp[e] = Bw[(size_t)k * N + n + e];
                v4 = make_float4(tmp[0], tmp[1], tmp[2], tmp[3]);
            }
            *(float4*)&Bs[kb][nb] = v4;
        }
        __syncthreads();
#pragma unroll
        for (int kk = 0; kk < 16; ++kk) {
            float4 a0 = *(const float4*)&As[kk][ty * 8];
            float4 a1 = *(const float4*)&As[kk][ty * 8 + 4];
            float4 b0 = *(const float4*)&Bs[kk][tx * 4];
            float av[8] = {a0.x, a0.y, a0.z, a0.w, a1.x, a1.y, a1.z, a1.w};
            float bv[4] = {b0.x, b0.y, b0.z, b0.w};
#pragma unroll
            for (int i = 0; i < 8; ++i)
#pragma unroll
                for (int j = 0; j < 4; ++j)
                    acc[i][j] = fmaf(av[i], bv[j], acc[i][j]);
        }
        __syncthreads();
    }
#pragma unroll
    for (int i = 0; i < 8; ++i) {
        int mm = m0 + ty * 8 + i;
#pragma unroll
        for (int j = 0; j < 4; ++j) {
            int n = n0 + tx * 4 + j;
            if (n < N) {
                float v = acc[i][j] + bias[n];
                v = (ACT == 0) ? fmaxf(v, 0.f) : 1.f / (1.f + expf(-v));
                out[(size_t)mm * N + n] = v;
            }
        }
    }
}

// ------------------------- host launcher ------------------------------------
extern "C" void kernel_launch(void* const* d_in, const int* in_sizes, int n_in,
                              void* d_out, int out_size, void* d_ws, size_t ws_size,
                              hipStream_t stream)
{
    const float* x       = (const float*)d_in[0];
    const float* conv1_w = (const float*)d_in[1];
    const float* conv1_b = (const float*)d_in[2];
    const float* prim_w  = (const float*)d_in[3];
    const float* prim_b  = (const float*)d_in[4];
    const float* route_w = (const float*)d_in[5];
    const float* dec_w1  = (const float*)d_in[6];
    const float* dec_b1  = (const float*)d_in[7];
    const float* dec_w2  = (const float*)d_in[8];
    const float* dec_b2  = (const float*)d_in[9];
    const float* dec_w3  = (const float*)d_in[10];
    const float* dec_b3  = (const float*)d_in[11];

    float* ws     = (float*)d_ws;
    float* wT1    = ws;
    float* wTp    = wT1 + N_WT1;
    float* p      = wTp + N_WTP;
    float* caps   = p + N_P;
    float* masked = caps + N_CAPS;
    float* d1     = masked + N_MASKED;
    float* d2     = d1 + N_D1;
    float* h      = d2 + N_D2;           // chunk*102400 floats
    float* outF   = (float*)d_out;

    const size_t fixedf = (size_t)N_WT1 + N_WTP + N_P + N_CAPS + N_MASKED + N_D1 + N_D2;
    int chunk = 32;
    const int cand[5] = {512, 256, 128, 64, 32};
    for (int i = 0; i < 5; ++i) {
        if ((fixedf + (size_t)cand[i] * 102400ull) * sizeof(float) <= ws_size) {
            chunk = cand[i];
            break;
        }
    }

    // weight transposes (K-major, permuted k-order)
    transpose_perm<3><<<dim3(4, 4), 256, 0, stream>>>(conv1_w, wT1, 256, 243);
    transpose_perm<256><<<dim3(324, 4), 256, 0, stream>>>(prim_w, wTp, 256, 20736);

    const int nchunks = 1024 / chunk;
    for (int ci = 0; ci < nchunks; ++ci) {
        const float* xin = x + (size_t)ci * chunk * 2352;
        conv_gemm<3, 28, 28, 1, 20, 20, 243, 0>
            <<<dim3(chunk * 400 / 128, 4), 256, 0, stream>>>(xin, wT1, conv1_b, h, 0);
        conv_gemm<256, 20, 20, 2, 6, 6, 20736, 1>
            <<<dim3(chunk * 36 / 128, 4), 256, 0, stream>>>(h, wTp, prim_b, p, ci * chunk);
    }

    routing_kernel<<<dim3(1024, 2), 256, 0, stream>>>(p, route_w, caps);
    mask_kernel<<<4, 256, 0, stream>>>(caps, outF, masked);

    dense_gemm<0><<<dim3(8, 8),  256, 0, stream>>>(masked, dec_w1, dec_b1, d1, 1024, 512, 32);
    dense_gemm<0><<<dim3(8, 16), 256, 0, stream>>>(d1, dec_w2, dec_b2, d2, 1024, 1024, 512);
    dense_gemm<1><<<dim3(8, 13), 256, 0, stream>>>(d2, dec_w3, dec_b3, outF + 2048, 1024, 784, 1024);
}

// Round 2
// 10001.376 us; speedup vs baseline: 2.1973x; 2.1973x over previous
//
#include <hip/hip_runtime.h>
#include <hip/hip_bf16.h>
#include <cmath>
#include <cstdint>

// ---------------------------------------------------------------------------
// CapsuleNet forward, fp32. Round 2: locality-fixed implicit-GEMM convs.
//   - h stored NHWC (b, y, x, c): conv1 writes coalesced float4; prim conv
//     stages A as float4 of 16 consecutive channels (one 64B line per step).
//   - conv tiles 64x256 (full N), 256 thr, 8x8 micro, BK=16, register-prefetch
//     pipeline (global loads for step s+1 issued before compute of step s).
//   - prim conv split-K x4 along channels, atomicAdd epilogue into p.
//   - routing/mask/decoder unchanged from round 1 (correct, not yet hot).
// ---------------------------------------------------------------------------

#define N_WT1     62208       // 243*256
#define N_WTP     5308416     // 20736*256
#define N_P       9437184     // 1024*1152*8
#define N_CAPS    32768       // 1024*2*16
#define N_MASKED  32768       // 1024*32
#define N_D1      524288      // 1024*512
#define N_D2      1048576     // 1024*1024

// ------------------------- weight transposes --------------------------------
// plain: wT[k][n] = w[n][k]   (conv1, k = c*81+khw, c-major)
__global__ void __launch_bounds__(256) transpose_plain(
    const float* __restrict__ w, float* __restrict__ wT, int N, int K)
{
    __shared__ float tile[64][65];
    const int k0 = blockIdx.x * 64, n0 = blockIdx.y * 64;
    const int t = threadIdx.x;
    const int kk = t & 63;
    for (int nn = t >> 6; nn < 64; nn += 4) {
        int n = n0 + nn, k = k0 + kk;
        tile[nn][kk] = (n < N && k < K) ? w[(size_t)n * K + k] : 0.f;
    }
    __syncthreads();
    const int nn = t & 63;
    for (int kk2 = t >> 6; kk2 < 64; kk2 += 4) {
        int n = n0 + nn, k = k0 + kk2;
        if (n < N && k < K) wT[(size_t)k * N + n] = tile[nn][kk2];
    }
}

// permuted: wT[(khw*CIN + c)][n] = w[n][c*81+khw]   (prim, khw-major K order)
template<int CIN>
__global__ void __launch_bounds__(256) transpose_perm(
    const float* __restrict__ w, float* __restrict__ wT, int N, int K)
{
    __shared__ float tile[64][65];
    const int k0 = blockIdx.x * 64, n0 = blockIdx.y * 64;
    const int t = threadIdx.x;
    const int kk = t & 63;
    for (int nn = t >> 6; nn < 64; nn += 4) {
        int n = n0 + nn, k = k0 + kk;
        tile[nn][kk] = (n < N && k < K) ? w[(size_t)n * K + k] : 0.f;
    }
    __syncthreads();
    const int nn = t & 63;
    for (int kk2 = t >> 6; kk2 < 64; kk2 += 4) {
        int n = n0 + nn, k = k0 + kk2;
        if (n < N && k < K) {
            int c = k / 81, khw = k % 81;
            wT[((size_t)khw * CIN + c) * N + n] = tile[nn][kk2];
        }
    }
}

// ------------------------- implicit-GEMM conv, 64x256 tile ------------------
// MODE 0: conv1. in = x (NCHW 3x28x28), K = 243 c-major, out = h NHWC, ReLU.
// MODE 1: prim.  in = h (NHWC 20x20x256), K = 81*256 khw-major, split-K over
//                channel quarters (blockIdx.y = kz), out = p via atomicAdd.
template<int MODE>
__global__ void __launch_bounds__(256) conv_gemm2(
    const float* __restrict__ in, const float* __restrict__ wT,
    const float* __restrict__ bias, float* __restrict__ out, int b_base)
{
    constexpr int NSTEPS = (MODE == 0) ? 16 : 324;   // mode1: 81 khw * 4 c-steps
    __shared__ __align__(16) float As[16][64];
    __shared__ __align__(16) float Bs[16][256];
    __shared__ int otab[81];

    const int t  = threadIdx.x;
    const int m0 = blockIdx.x * 64;
    const int kz = blockIdx.y;                       // split-k id (MODE 1)

    // ---- A staging coords: thread loads k rows [k4,k4+4) of column m ----
    const int m_l = t & 63;
    const int k4  = (t >> 6) * 4;                    // {0,4,8,12}, wave-uniform
    const int m   = m0 + m_l;
    const float* aptr;
    if (MODE == 0) {
        int bb = m / 400, pp = m - bb * 400;
        int py = pp / 20, px = pp - py * 20;
        aptr = in + (size_t)bb * 2352 + py * 28 + px;   // + c*784 + otab[khw]
        if (t < 81) otab[t] = (t / 9) * 28 + (t % 9);
    } else {
        int bb = m / 36, pix = m - bb * 36;
        int py = pix / 6, px = pix - py * 6;
        aptr = in + ((size_t)bb * 400 + py * 2 * 20 + px * 2) * 256; // + (ky*20+kx)*256 + c
    }
    // ---- B staging coords: thread loads float4 at rows kb+4q, cols nb ----
    const int nb = (t & 63) * 4;
    const int kb = t >> 6;
    // ---- micro-tile coords ----
    const int tx = t & 31, ty = t >> 5;

    float acc[8][8];
#pragma unroll
    for (int i = 0; i < 8; ++i)
#pragma unroll
        for (int j = 0; j < 8; ++j) acc[i][j] = 0.f;

    float  aP[4];
    float4 bP[4];

    auto stage = [&](int s) {
        if (MODE == 0) {
            int kb0 = s * 16;
#pragma unroll
            for (int j = 0; j < 4; ++j) {
                int k = kb0 + k4 + j;                 // wave-uniform
                int c = k / 81, khw = k - c * 81;
                aP[j] = (k < 243) ? aptr[c * 784 + otab[khw]] : 0.f;
            }
#pragma unroll
            for (int q = 0; q < 4; ++q) {
                int k = kb0 + kb + q * 4;
                bP[q] = (k < 243) ? *(const float4*)&wT[(size_t)k * 256 + nb]
                                  : make_float4(0.f, 0.f, 0.f, 0.f);
            }
        } else {
            int khw = s >> 2;
            int cc  = kz * 64 + (s & 3) * 16;
            int ky  = khw / 9, kx = khw - ky * 9;
            int rowoff = (ky * 20 + kx) * 256;
            float4 av = *(const float4*)&aptr[rowoff + cc + k4];
            aP[0] = av.x; aP[1] = av.y; aP[2] = av.z; aP[3] = av.w;
            int kgb = khw * 256 + cc;
#pragma unroll
            for (int q = 0; q < 4; ++q)
                bP[q] = *(const float4*)&wT[(size_t)(kgb + kb + q * 4) * 256 + nb];
        }
    };

    __syncthreads();                                  // otab visible (MODE 0)
    stage(0);

    for (int s = 0; s < NSTEPS; ++s) {
        __syncthreads();                              // LDS consumers done
#pragma unroll
        for (int j = 0; j < 4; ++j) As[k4 + j][m_l] = aP[j];
#pragma unroll
        for (int q = 0; q < 4; ++q) *(float4*)&Bs[kb + q * 4][nb] = bP[q];
        __syncthreads();
        if (s + 1 < NSTEPS) stage(s + 1);             // overlaps compute below
#pragma unroll
        for (int kk = 0; kk < 16; ++kk) {
            float4 a0 = *(const float4*)&As[kk][ty * 8];
            float4 a1 = *(const float4*)&As[kk][ty * 8 + 4];
            float4 b0 = *(const float4*)&Bs[kk][tx * 8];
            float4 b1 = *(const float4*)&Bs[kk][tx * 8 + 4];
            float av[8] = {a0.x, a0.y, a0.z, a0.w, a1.x, a1.y, a1.z, a1.w};
            float bv[8] = {b0.x, b0.y, b0.z, b0.w, b1.x, b1.y, b1.z, b1.w};
#pragma unroll
            for (int i = 0; i < 8; ++i)
#pragma unroll
                for (int j = 0; j < 8; ++j)
                    acc[i][j] = fmaf(av[i], bv[j], acc[i][j]);
        }
    }

    // ---- epilogue ----
    if (MODE == 0) {
        float bj[8];
#pragma unroll
        for (int j = 0; j < 8; ++j) bj[j] = bias[tx * 8 + j];
#pragma unroll
        for (int i = 0; i < 8; ++i) {
            int mm = m0 + ty * 8 + i;
            float4 o0, o1;
            o0.x = fmaxf(acc[i][0] + bj[0], 0.f);
            o0.y = fmaxf(acc[i][1] + bj[1], 0.f);
            o0.z = fmaxf(acc[i][2] + bj[2], 0.f);
            o0.w = fmaxf(acc[i][3] + bj[3], 0.f);
            o1.x = fmaxf(acc[i][4] + bj[4], 0.f);
            o1.y = fmaxf(acc[i][5] + bj[5], 0.f);
            o1.z = fmaxf(acc[i][6] + bj[6], 0.f);
            o1.w = fmaxf(acc[i][7] + bj[7], 0.f);
            *(float4*)&out[(size_t)mm * 256 + tx * 8]     = o0;
            *(float4*)&out[(size_t)mm * 256 + tx * 8 + 4] = o1;
        }
    } else {
        float bj[8];
#pragma unroll
        for (int j = 0; j < 8; ++j) bj[j] = (kz == 0) ? bias[tx * 8 + j] : 0.f;
#pragma unroll
        for (int i = 0; i < 8; ++i) {
            int mm = m0 + ty * 8 + i;
            int bb = mm / 36, pix = mm - bb * 36;
            float* pp = out + (((size_t)(b_base + bb) * 1152) + tx * 36 + pix) * 8;
#pragma unroll
            for (int j = 0; j < 8; ++j)
                atomicAdd(&pp[j], acc[i][j] + bj[j]);
        }
    }
}

// ------------------------- dynamic routing ----------------------------------
// grid (1024, 2): block per (b, c). 256 threads; r = t + 256*j (j<5).
__global__ void __launch_bounds__(256) routing_kernel(
    const float* __restrict__ p, const float* __restrict__ rw,
    float* __restrict__ caps)
{
    const int b = blockIdx.x;
    const int c = blockIdx.y;
    const int t = threadIdx.x;
    const int lane = t & 63, wid = t >> 6;
    __shared__ float redbuf[4];
    __shared__ float tred[4][16];
    __shared__ float outv[16];

    const float* pb  = p  + (size_t)b * 9216;
    const float* rwc = rw + (size_t)c * 147456;

    float p_loc[5][8];
    float l_loc[5];
#pragma unroll
    for (int j = 0; j < 5; ++j) {
        l_loc[j] = 0.f;
        int r = t + 256 * j;
        if (j < 4 || t < 128) {
            float4 v0 = *(const float4*)&pb[(size_t)r * 8];
            float4 v1 = *(const float4*)&pb[(size_t)r * 8 + 4];
            p_loc[j][0] = v0.x; p_loc[j][1] = v0.y; p_loc[j][2] = v0.z; p_loc[j][3] = v0.w;
            p_loc[j][4] = v1.x; p_loc[j][5] = v1.y; p_loc[j][6] = v1.z; p_loc[j][7] = v1.w;
        } else {
#pragma unroll
            for (int i = 0; i < 8; ++i) p_loc[j][i] = 0.f;
        }
    }

    for (int it = 0; it < 3; ++it) {
        float lm = -1e30f;
#pragma unroll
        for (int j = 0; j < 5; ++j) if (j < 4 || t < 128) lm = fmaxf(lm, l_loc[j]);
#pragma unroll
        for (int off = 32; off; off >>= 1) lm = fmaxf(lm, __shfl_down(lm, off, 64));
        __syncthreads();
        if (lane == 0) redbuf[wid] = lm;
        __syncthreads();
        lm = fmaxf(fmaxf(redbuf[0], redbuf[1]), fmaxf(redbuf[2], redbuf[3]));

        float e_loc[5];
        float ls = 0.f;
#pragma unroll
        for (int j = 0; j < 5; ++j) {
            e_loc[j] = 0.f;
            if (j < 4 || t < 128) { e_loc[j] = __expf(l_loc[j] - lm); ls += e_loc[j]; }
        }
#pragma unroll
        for (int off = 32; off; off >>= 1) ls += __shfl_down(ls, off, 64);
        __syncthreads();
        if (lane == 0) redbuf[wid] = ls;
        __syncthreads();
        ls = redbuf[0] + redbuf[1] + redbuf[2] + redbuf[3];
        const float inv = 1.f / ls;

        float tv[16];
#pragma unroll
        for (int v = 0; v < 16; ++v) tv[v] = 0.f;
#pragma unroll
        for (int j = 0; j < 5; ++j) {
            if (j < 4 || t < 128) {
                int r = t + 256 * j;
                const float* wr = rwc + (size_t)r * 128;
#pragma unroll
                for (int i = 0; i < 8; ++i) {
                    float q = e_loc[j] * p_loc[j][i];
#pragma unroll
                    for (int v4 = 0; v4 < 4; ++v4) {
                        float4 w4 = *(const float4*)&wr[i * 16 + v4 * 4];
                        tv[v4 * 4 + 0] = fmaf(q, w4.x, tv[v4 * 4 + 0]);
                        tv[v4 * 4 + 1] = fmaf(q, w4.y, tv[v4 * 4 + 1]);
                        tv[v4 * 4 + 2] = fmaf(q, w4.z, tv[v4 * 4 + 2]);
                        tv[v4 * 4 + 3] = fmaf(q, w4.w, tv[v4 * 4 + 3]);
                    }
                }
            }
        }
#pragma unroll
        for (int v = 0; v < 16; ++v) {
            float xv = tv[v];
#pragma unroll
            for (int off = 32; off; off >>= 1) xv += __shfl_down(xv, off, 64);
            tv[v] = xv;
        }
        __syncthreads();
        if (lane == 0) {
#pragma unroll
            for (int v = 0; v < 16; ++v) tred[wid][v] = tv[v];
        }
        __syncthreads();
        if (t < 16) outv[t] = (tred[0][t] + tred[1][t] + tred[2][t] + tred[3][t]) * inv;
        __syncthreads();

        float s2 = 0.f;
#pragma unroll
        for (int v = 0; v < 16; ++v) s2 += outv[v] * outv[v];
        const float scale = s2 / ((1.f + s2) * sqrtf(s2));

        if (it == 2) {
            if (t < 16) caps[((size_t)b * 2 + c) * 16 + t] = scale * outv[t];
        } else {
            float ov[16];
#pragma unroll
            for (int v = 0; v < 16; ++v) ov[v] = scale * outv[v];
#pragma unroll
            for (int j = 0; j < 5; ++j) {
                if (j < 4 || t < 128) {
                    int r = t + 256 * j;
                    const float* wr = rwc + (size_t)r * 128;
                    float d = 0.f;
#pragma unroll
                    for (int i = 0; i < 8; ++i) {
                        float u = 0.f;
#pragma unroll
                        for (int v4 = 0; v4 < 4; ++v4) {
                            float4 w4 = *(const float4*)&wr[i * 16 + v4 * 4];
                            u = fmaf(w4.x, ov[v4 * 4 + 0], u);
                            u = fmaf(w4.y, ov[v4 * 4 + 1], u);
                            u = fmaf(w4.z, ov[v4 * 4 + 2], u);
                            u = fmaf(w4.w, ov[v4 * 4 + 3], u);
                        }
                        d = fmaf(p_loc[j][i], u, d);
                    }
                    l_loc[j] += d;
                }
            }
            __syncthreads();
        }
    }
}

// ------------------------- class softmax + argmax mask ----------------------
__global__ void __launch_bounds__(256) mask_kernel(
    const float* __restrict__ caps, float* __restrict__ cls_out,
    float* __restrict__ masked)
{
    int b = blockIdx.x * 256 + threadIdx.x;
    if (b < 1024) {
        const float* cb = caps + (size_t)b * 32;
        float n0 = 0.f, n1 = 0.f;
#pragma unroll
        for (int v = 0; v < 16; ++v) {
            n0 = fmaf(cb[v], cb[v], n0);
            n1 = fmaf(cb[16 + v], cb[16 + v], n1);
        }
        n0 = sqrtf(n0); n1 = sqrtf(n1);
        float mx = fmaxf(n0, n1);
        float e0 = expf(n0 - mx), e1 = expf(n1 - mx);
        float inv = 1.f / (e0 + e1);
        cls_out[b * 2 + 0] = e0 * inv;
        cls_out[b * 2 + 1] = e1 * inv;
        int cs = (n1 > n0) ? 1 : 0;
#pragma unroll
        for (int v = 0; v < 16; ++v) {
            masked[(size_t)b * 32 + v]      = (cs == 0) ? cb[v] : 0.f;
            masked[(size_t)b * 32 + 16 + v] = (cs == 1) ? cb[16 + v] : 0.f;
        }
    }
}

// ------------------------- decoder GEMM -------------------------------------
template<int ACT>
__global__ void __launch_bounds__(256) dense_gemm(
    const float* __restrict__ A, const float* __restrict__ Bw,
    const float* __restrict__ bias, float* __restrict__ out,
    int M, int N, int K)
{
    __shared__ __align__(16) float As[16][128];
    __shared__ __align__(16) float Bs[16][64];
    const int t  = threadIdx.x;
    const int m0 = blockIdx.x * 128, n0 = blockIdx.y * 64;
    const int tx = t & 15, ty = t >> 4;
    const int am = t >> 1;
    const int ak = (t & 1) * 8;
    const int nb = (t & 15) * 4, kb = t >> 4;

    float acc[8][4];
#pragma unroll
    for (int i = 0; i < 8; ++i)
#pragma unroll
        for (int j = 0; j < 4; ++j) acc[i][j] = 0.f;

    for (int k0i = 0; k0i < K; k0i += 16) {
        {
            const float* ap = A + (size_t)(m0 + am) * K + k0i + ak;
            float4 v0 = *(const float4*)ap;
            float4 v1 = *(const float4*)(ap + 4);
            As[ak + 0][am] = v0.x; As[ak + 1][am] = v0.y;
            As[ak + 2][am] = v0.z; As[ak + 3][am] = v0.w;
            As[ak + 4][am] = v1.x; As[ak + 5][am] = v1.y;
            As[ak + 6][am] = v1.z; As[ak + 7][am] = v1.w;
        }
        {
            int k = k0i + kb;
            int n = n0 + nb;
            float4 v4 = make_float4(0.f, 0.f, 0.f, 0.f);
            if (n + 3 < N) {
                v4 = *(const float4*)&Bw[(size_t)k * N + n];
            } else {
                float tmp[4] = {0.f, 0.f, 0.f, 0.f};
#pragma unroll
                for (int e = 0; e < 4; ++e)
                    if (n + e < N) tmp[e] = Bw[(size_t)k * N + n + e];
                v4 = make_float4(tmp[0], tmp[1], tmp[2], tmp[3]);
            }
            *(float4*)&Bs[kb][nb] = v4;
        }
        __syncthreads();
#pragma unroll
        for (int kk = 0; kk < 16; ++kk) {
            float4 a0 = *(const float4*)&As[kk][ty * 8];
            float4 a1 = *(const float4*)&As[kk][ty * 8 + 4];
            float4 b0 = *(const float4*)&Bs[kk][tx * 4];
            float av[8] = {a0.x, a0.y, a0.z, a0.w, a1.x, a1.y, a1.z, a1.w};
            float bv[4] = {b0.x, b0.y, b0.z, b0.w};
#pragma unroll
            for (int i = 0; i < 8; ++i)
#pragma unroll
                for (int j = 0; j < 4; ++j)
                    acc[i][j] = fmaf(av[i], bv[j], acc[i][j]);
        }
        __syncthreads();
    }
#pragma unroll
    for (int i = 0; i < 8; ++i) {
        int mm = m0 + ty * 8 + i;
#pragma unroll
        for (int j = 0; j < 4; ++j) {
            int n = n0 + tx * 4 + j;
            if (n < N) {
                float v = acc[i][j] + bias[n];
                v = (ACT == 0) ? fmaxf(v, 0.f) : 1.f / (1.f + expf(-v));
                out[(size_t)mm * N + n] = v;
            }
        }
    }
}

// ------------------------- host launcher ------------------------------------
extern "C" void kernel_launch(void* const* d_in, const int* in_sizes, int n_in,
                              void* d_out, int out_size, void* d_ws, size_t ws_size,
                              hipStream_t stream)
{
    const float* x       = (const float*)d_in[0];
    const float* conv1_w = (const float*)d_in[1];
    const float* conv1_b = (const float*)d_in[2];
    const float* prim_w  = (const float*)d_in[3];
    const float* prim_b  = (const float*)d_in[4];
    const float* route_w = (const float*)d_in[5];
    const float* dec_w1  = (const float*)d_in[6];
    const float* dec_b1  = (const float*)d_in[7];
    const float* dec_w2  = (const float*)d_in[8];
    const float* dec_b2  = (const float*)d_in[9];
    const float* dec_w3  = (const float*)d_in[10];
    const float* dec_b3  = (const float*)d_in[11];

    float* ws     = (float*)d_ws;
    float* wT1    = ws;
    float* wTp    = wT1 + N_WT1;
    float* p      = wTp + N_WTP;
    float* caps   = p + N_P;
    float* masked = caps + N_CAPS;
    float* d1     = masked + N_MASKED;
    float* d2     = d1 + N_D1;
    float* h      = d2 + N_D2;           // chunk * 400 * 256 floats, NHWC
    float* outF   = (float*)d_out;

    const size_t fixedf = (size_t)N_WT1 + N_WTP + N_P + N_CAPS + N_MASKED + N_D1 + N_D2;
    int chunk = 128;
    const int cand[4] = {1024, 512, 256, 128};
    for (int i = 0; i < 4; ++i) {
        if ((fixedf + (size_t)cand[i] * 102400ull) * sizeof(float) <= ws_size) {
            chunk = cand[i];
            break;
        }
    }

    // p must be zeroed: prim conv accumulates with atomics (split-K).
    hipMemsetAsync(p, 0, (size_t)N_P * sizeof(float), stream);

    // weight transposes
    transpose_plain<<<dim3(4, 4), 256, 0, stream>>>(conv1_w, wT1, 256, 243);
    transpose_perm<256><<<dim3(324, 4), 256, 0, stream>>>(prim_w, wTp, 256, 20736);

    const int nchunks = 1024 / chunk;
    for (int ci = 0; ci < nchunks; ++ci) {
        const float* xin = x + (size_t)ci * chunk * 2352;
        conv_gemm2<0><<<dim3(chunk * 400 / 64), 256, 0, stream>>>(xin, wT1, conv1_b, h, 0);
        conv_gemm2<1><<<dim3(chunk * 36 / 64, 4), 256, 0, stream>>>(h, wTp, prim_b, p, ci * chunk);
    }

    routing_kernel<<<dim3(1024, 2), 256, 0, stream>>>(p, route_w, caps);
    mask_kernel<<<4, 256, 0, stream>>>(caps, outF, masked);

    dense_gemm<0><<<dim3(8, 8),  256, 0, stream>>>(masked, dec_w1, dec_b1, d1, 1024, 512, 32);
    dense_gemm<0><<<dim3(8, 16), 256, 0, stream>>>(d1, dec_w2, dec_b2, d2, 1024, 1024, 512);
    dense_gemm<1><<<dim3(8, 13), 256, 0, stream>>>(d2, dec_w3, dec_b3, outF + 2048, 1024, 784, 1024);
}

// Round 3
// 4345.348 us; speedup vs baseline: 5.0573x; 2.3016x over previous
//
#include <hip/hip_runtime.h>
#include <hip/hip_bf16.h>
#include <cmath>
#include <cstdint>

// ---------------------------------------------------------------------------
// CapsuleNet forward. Round 3: prim conv via fp16 split-precision MFMA.
//   value = hi + lo * 2^-11  (both fp16; lo stored pre-scaled by 2^11)
//   C = acc_hh + 2^-11 * acc_x,  acc_x = hi*lo' + lo'*hi   (lo.lo dropped)
//   Per-block 64x64 tile, 4 waves (2x2), 32x32/wave, 16x16x32 f16 MFMA,
//   BK=64 (one khw x 64 channels), XOR-swizzled LDS (conflict-free b128).
// conv1 stays fp32-vector; epilogue emits h as fp16 hi/lo NHWC.
// ---------------------------------------------------------------------------

typedef _Float16 f16;
typedef _Float16 f16x8 __attribute__((ext_vector_type(8)));
typedef float    f32x4 __attribute__((ext_vector_type(4)));

// ------------------------- conv1 weight transpose (fp32, K-major) -----------
__global__ void __launch_bounds__(256) transpose_plain(
    const float* __restrict__ w, float* __restrict__ wT, int N, int K)
{
    __shared__ float tile[64][65];
    const int k0 = blockIdx.x * 64, n0 = blockIdx.y * 64;
    const int t = threadIdx.x;
    const int kk = t & 63;
    for (int nn = t >> 6; nn < 64; nn += 4) {
        int n = n0 + nn, k = k0 + kk;
        tile[nn][kk] = (n < N && k < K) ? w[(size_t)n * K + k] : 0.f;
    }
    __syncthreads();
    const int nn = t & 63;
    for (int kk2 = t >> 6; kk2 < 64; kk2 += 4) {
        int n = n0 + nn, k = k0 + kk2;
        if (n < N && k < K) wT[(size_t)k * N + n] = tile[nn][kk2];
    }
}

// ------------------------- prim weight: permute + fp16 split ----------------
// in : w[n][c*81+khw]  (n=0..255 outputs, row 20736)
// out: whT/wlT [n][khw*256+c]  (n-major rows of 20736 f16)
__global__ void __launch_bounds__(256) transpose_split_w(
    const float* __restrict__ w, f16* __restrict__ whT, f16* __restrict__ wlT)
{
    __shared__ float tile[5184];                  // 64 c x 81 khw
    const int n  = blockIdx.x;                    // 0..255
    const int cq = blockIdx.y;                    // 0..3 (c quarter)
    const int t  = threadIdx.x;
    const float* wr = w + (size_t)n * 20736 + cq * 5184;
    for (int i = t; i < 5184; i += 256) tile[i] = wr[i];
    __syncthreads();
    f16* oh = whT + (size_t)n * 20736 + cq * 64;
    f16* ol = wlT + (size_t)n * 20736 + cq * 64;
    for (int j = t; j < 5184; j += 256) {
        int khw = j >> 6, c = j & 63;
        float v  = tile[c * 81 + khw];
        f16 hi   = (f16)v;
        f16 lo   = (f16)((v - (float)hi) * 2048.0f);
        oh[khw * 256 + c] = hi;
        ol[khw * 256 + c] = lo;
    }
}

// ------------------------- conv1: fp32 implicit GEMM, 64x256 tile -----------
// in = x (NCHW 3x28x28), K = 243 c-major. out: hh/hl fp16 NHWC (b,y,x,c).
__global__ void __launch_bounds__(256) conv1_gemm(
    const float* __restrict__ in, const float* __restrict__ wT,
    const float* __restrict__ bias, f16* __restrict__ hh, f16* __restrict__ hl)
{
    __shared__ __align__(16) float As[16][64];
    __shared__ __align__(16) float Bs[16][256];
    __shared__ int otab[81];

    const int t  = threadIdx.x;
    const int m0 = blockIdx.x * 64;

    const int m_l = t & 63;
    const int k4  = (t >> 6) * 4;                 // wave-uniform
    const int m   = m0 + m_l;
    int bb = m / 400, pp = m - bb * 400;
    int py = pp / 20, px = pp - py * 20;
    const float* aptr = in + (size_t)bb * 2352 + py * 28 + px;
    if (t < 81) otab[t] = (t / 9) * 28 + (t % 9);

    const int nb = (t & 63) * 4;
    const int kb = t >> 6;
    const int tx = t & 31, ty = t >> 5;

    float acc[8][8];
#pragma unroll
    for (int i = 0; i < 8; ++i)
#pragma unroll
        for (int j = 0; j < 8; ++j) acc[i][j] = 0.f;

    float  aP[4];
    float4 bP[4];

    auto stage = [&](int s) {
        int kb0 = s * 16;
#pragma unroll
        for (int j = 0; j < 4; ++j) {
            int k = kb0 + k4 + j;
            int c = k / 81, khw = k - c * 81;
            aP[j] = (k < 243) ? aptr[c * 784 + otab[khw]] : 0.f;
        }
#pragma unroll
        for (int q = 0; q < 4; ++q) {
            int k = kb0 + kb + q * 4;
            bP[q] = (k < 243) ? *(const float4*)&wT[(size_t)k * 256 + nb]
                              : make_float4(0.f, 0.f, 0.f, 0.f);
        }
    };

    __syncthreads();                              // otab ready
    stage(0);

    for (int s = 0; s < 16; ++s) {
        __syncthreads();
#pragma unroll
        for (int j = 0; j < 4; ++j) As[k4 + j][m_l] = aP[j];
#pragma unroll
        for (int q = 0; q < 4; ++q) *(float4*)&Bs[kb + q * 4][nb] = bP[q];
        __syncthreads();
        if (s + 1 < 16) stage(s + 1);
#pragma unroll
        for (int kk = 0; kk < 16; ++kk) {
            float4 a0 = *(const float4*)&As[kk][ty * 8];
            float4 a1 = *(const float4*)&As[kk][ty * 8 + 4];
            float4 b0 = *(const float4*)&Bs[kk][tx * 8];
            float4 b1 = *(const float4*)&Bs[kk][tx * 8 + 4];
            float av[8] = {a0.x, a0.y, a0.z, a0.w, a1.x, a1.y, a1.z, a1.w};
            float bv[8] = {b0.x, b0.y, b0.z, b0.w, b1.x, b1.y, b1.z, b1.w};
#pragma unroll
            for (int i = 0; i < 8; ++i)
#pragma unroll
                for (int j = 0; j < 8; ++j)
                    acc[i][j] = fmaf(av[i], bv[j], acc[i][j]);
        }
    }

    float bj[8];
#pragma unroll
    for (int j = 0; j < 8; ++j) bj[j] = bias[tx * 8 + j];
#pragma unroll
    for (int i = 0; i < 8; ++i) {
        int mm = m0 + ty * 8 + i;
        f16x8 vhi, vlo;
#pragma unroll
        for (int j = 0; j < 8; ++j) {
            float o = fmaxf(acc[i][j] + bj[j], 0.f);
            f16 h_  = (f16)o;
            vhi[j]  = h_;
            vlo[j]  = (f16)((o - (float)h_) * 2048.0f);
        }
        *(f16x8*)&hh[(size_t)mm * 256 + tx * 8] = vhi;
        *(f16x8*)&hl[(size_t)mm * 256 + tx * 8] = vlo;
    }
}

// ------------------------- prim conv: fp16-split MFMA -----------------------
// GEMM: C[M=chunk*36, 256] = im2col(h)[M, 20736] * W[20736, 256]
// K order: k = khw*256 + c (khw-major). Step s: khw = s>>2, c-quarter = s&3.
// LDS XOR swizzle: element (row r, k-group g) at halves-offset
//   r*64 + ((g ^ (r&7))*8)   -> conflict-free b128 reads and writes.
__global__ void __launch_bounds__(256) prim_mfma(
    const f16* __restrict__ hh, const f16* __restrict__ hl,
    const f16* __restrict__ whT, const f16* __restrict__ wlT,
    const float* __restrict__ bias, float* __restrict__ p, int b_base)
{
    __shared__ __align__(16) f16 Ah[4096], Al[4096], Bh[4096], Bl[4096];
    const int t  = threadIdx.x;
    const int m0 = blockIdx.x * 64;
    const int n0 = blockIdx.y * 64;

    // ---- staging coords: thread -> (row = p*32 + t>>3, k-group = t&7) ----
    const int sr = t >> 3;
    const int sg = t & 7;
    int abase[2], bbase[2], wofs[2];
#pragma unroll
    for (int pp = 0; pp < 2; ++pp) {
        int m  = m0 + pp * 32 + sr;
        int bb = m / 36, pix = m - bb * 36;
        int py = pix / 6, px = pix - py * 6;
        abase[pp] = ((bb * 400 + py * 40 + px * 2) << 8) + sg * 8;
        bbase[pp] = (n0 + pp * 32 + sr) * 20736 + sg * 8;
        int r = pp * 32 + sr;
        wofs[pp] = r * 64 + ((sg ^ (r & 7)) * 8);
    }

    f16x8 rAh[2], rAl[2], rBh[2], rBl[2];
    auto stage = [&](int s) {
        int khw = s >> 2;
        int ky = khw / 9, kx = khw - ky * 9;
        int aoff = (ky * 20 + kx) * 256 + (s & 3) * 64;
        int boff = s * 64;
#pragma unroll
        for (int pp = 0; pp < 2; ++pp) {
            rAh[pp] = *(const f16x8*)&hh[abase[pp] + aoff];
            rAl[pp] = *(const f16x8*)&hl[abase[pp] + aoff];
            rBh[pp] = *(const f16x8*)&whT[bbase[pp] + boff];
            rBl[pp] = *(const f16x8*)&wlT[bbase[pp] + boff];
        }
    };

    // ---- wave/lane coords ----
    const int lane = t & 63;
    const int wv   = t >> 6;
    const int wm   = wv >> 1, wn = wv & 1;       // 2x2 wave grid
    const int li   = lane & 15, lq = lane >> 4;

    f32x4 acc_h[2][2], acc_x[2][2];
#pragma unroll
    for (int i = 0; i < 2; ++i)
#pragma unroll
        for (int j = 0; j < 2; ++j) {
            acc_h[i][j] = (f32x4){0.f, 0.f, 0.f, 0.f};
            acc_x[i][j] = (f32x4){0.f, 0.f, 0.f, 0.f};
        }

    stage(0);

    for (int s = 0; s < 324; ++s) {
        __syncthreads();                          // LDS consumers done
#pragma unroll
        for (int pp = 0; pp < 2; ++pp) {
            *(f16x8*)&Ah[wofs[pp]] = rAh[pp];
            *(f16x8*)&Al[wofs[pp]] = rAl[pp];
            *(f16x8*)&Bh[wofs[pp]] = rBh[pp];
            *(f16x8*)&Bl[wofs[pp]] = rBl[pp];
        }
        __syncthreads();
        if (s + 1 < 324) stage(s + 1);            // overlaps MFMA below
#pragma unroll
        for (int h = 0; h < 2; ++h) {             // two K32 halves of BK=64
            int g = h * 4 + lq;
            f16x8 ah[2], al[2], bh[2], bl[2];
#pragma unroll
            for (int mf = 0; mf < 2; ++mf) {
                int r = wm * 32 + mf * 16 + li;
                int u = r * 64 + ((g ^ (r & 7)) * 8);
                ah[mf] = *(const f16x8*)&Ah[u];
                al[mf] = *(const f16x8*)&Al[u];
            }
#pragma unroll
            for (int nf = 0; nf < 2; ++nf) {
                int r = wn * 32 + nf * 16 + li;
                int u = r * 64 + ((g ^ (r & 7)) * 8);
                bh[nf] = *(const f16x8*)&Bh[u];
                bl[nf] = *(const f16x8*)&Bl[u];
            }
#pragma unroll
            for (int mf = 0; mf < 2; ++mf)
#pragma unroll
                for (int nf = 0; nf < 2; ++nf) {
                    acc_h[mf][nf] = __builtin_amdgcn_mfma_f32_16x16x32_f16(
                        ah[mf], bh[nf], acc_h[mf][nf], 0, 0, 0);
                    acc_x[mf][nf] = __builtin_amdgcn_mfma_f32_16x16x32_f16(
                        ah[mf], bl[nf], acc_x[mf][nf], 0, 0, 0);
                    acc_x[mf][nf] = __builtin_amdgcn_mfma_f32_16x16x32_f16(
                        al[mf], bh[nf], acc_x[mf][nf], 0, 0, 0);
                }
        }
    }

    // ---- epilogue: C/D layout col = lane&15, row = lq*4 + reg ----
    float bn[2];
    bn[0] = bias[n0 + wn * 32 + li];
    bn[1] = bias[n0 + wn * 32 + 16 + li];
#pragma unroll
    for (int mf = 0; mf < 2; ++mf) {
        int mb = m0 + wm * 32 + mf * 16 + lq * 4;
#pragma unroll
        for (int r = 0; r < 4; ++r) {
            int m  = mb + r;
            int bb = m / 36, pix = m - bb * 36;
            size_t rowp = (size_t)(b_base + bb) * 9216 + pix * 8;
#pragma unroll
            for (int nf = 0; nf < 2; ++nf) {
                int n   = n0 + wn * 32 + nf * 16 + li;
                int cap = n >> 3, vec = n & 7;
                float v = acc_h[mf][nf][r]
                        + acc_x[mf][nf][r] * (1.0f / 2048.0f) + bn[nf];
                p[rowp + cap * 288 + vec] = v;
            }
        }
    }
}

// ------------------------- dynamic routing ----------------------------------
__global__ void __launch_bounds__(256) routing_kernel(
    const float* __restrict__ p, const float* __restrict__ rw,
    float* __restrict__ caps)
{
    const int b = blockIdx.x;
    const int c = blockIdx.y;
    const int t = threadIdx.x;
    const int lane = t & 63, wid = t >> 6;
    __shared__ float redbuf[4];
    __shared__ float tred[4][16];
    __shared__ float outv[16];

    const float* pb  = p  + (size_t)b * 9216;
    const float* rwc = rw + (size_t)c * 147456;

    float p_loc[5][8];
    float l_loc[5];
#pragma unroll
    for (int j = 0; j < 5; ++j) {
        l_loc[j] = 0.f;
        int r = t + 256 * j;
        if (j < 4 || t < 128) {
            float4 v0 = *(const float4*)&pb[(size_t)r * 8];
            float4 v1 = *(const float4*)&pb[(size_t)r * 8 + 4];
            p_loc[j][0] = v0.x; p_loc[j][1] = v0.y; p_loc[j][2] = v0.z; p_loc[j][3] = v0.w;
            p_loc[j][4] = v1.x; p_loc[j][5] = v1.y; p_loc[j][6] = v1.z; p_loc[j][7] = v1.w;
        } else {
#pragma unroll
            for (int i = 0; i < 8; ++i) p_loc[j][i] = 0.f;
        }
    }

    for (int it = 0; it < 3; ++it) {
        float lm = -1e30f;
#pragma unroll
        for (int j = 0; j < 5; ++j) if (j < 4 || t < 128) lm = fmaxf(lm, l_loc[j]);
#pragma unroll
        for (int off = 32; off; off >>= 1) lm = fmaxf(lm, __shfl_down(lm, off, 64));
        __syncthreads();
        if (lane == 0) redbuf[wid] = lm;
        __syncthreads();
        lm = fmaxf(fmaxf(redbuf[0], redbuf[1]), fmaxf(redbuf[2], redbuf[3]));

        float e_loc[5];
        float ls = 0.f;
#pragma unroll
        for (int j = 0; j < 5; ++j) {
            e_loc[j] = 0.f;
            if (j < 4 || t < 128) { e_loc[j] = __expf(l_loc[j] - lm); ls += e_loc[j]; }
        }
#pragma unroll
        for (int off = 32; off; off >>= 1) ls += __shfl_down(ls, off, 64);
        __syncthreads();
        if (lane == 0) redbuf[wid] = ls;
        __syncthreads();
        ls = redbuf[0] + redbuf[1] + redbuf[2] + redbuf[3];
        const float inv = 1.f / ls;

        float tv[16];
#pragma unroll
        for (int v = 0; v < 16; ++v) tv[v] = 0.f;
#pragma unroll
        for (int j = 0; j < 5; ++j) {
            if (j < 4 || t < 128) {
                int r = t + 256 * j;
                const float* wr = rwc + (size_t)r * 128;
#pragma unroll
                for (int i = 0; i < 8; ++i) {
                    float q = e_loc[j] * p_loc[j][i];
#pragma unroll
                    for (int v4 = 0; v4 < 4; ++v4) {
                        float4 w4 = *(const float4*)&wr[i * 16 + v4 * 4];
                        tv[v4 * 4 + 0] = fmaf(q, w4.x, tv[v4 * 4 + 0]);
                        tv[v4 * 4 + 1] = fmaf(q, w4.y, tv[v4 * 4 + 1]);
                        tv[v4 * 4 + 2] = fmaf(q, w4.z, tv[v4 * 4 + 2]);
                        tv[v4 * 4 + 3] = fmaf(q, w4.w, tv[v4 * 4 + 3]);
                    }
                }
            }
        }
#pragma unroll
        for (int v = 0; v < 16; ++v) {
            float xv = tv[v];
#pragma unroll
            for (int off = 32; off; off >>= 1) xv += __shfl_down(xv, off, 64);
            tv[v] = xv;
        }
        __syncthreads();
        if (lane == 0) {
#pragma unroll
            for (int v = 0; v < 16; ++v) tred[wid][v] = tv[v];
        }
        __syncthreads();
        if (t < 16) outv[t] = (tred[0][t] + tred[1][t] + tred[2][t] + tred[3][t]) * inv;
        __syncthreads();

        float s2 = 0.f;
#pragma unroll
        for (int v = 0; v < 16; ++v) s2 += outv[v] * outv[v];
        const float scale = s2 / ((1.f + s2) * sqrtf(s2));

        if (it == 2) {
            if (t < 16) caps[((size_t)b * 2 + c) * 16 + t] = scale * outv[t];
        } else {
            float ov[16];
#pragma unroll
            for (int v = 0; v < 16; ++v) ov[v] = scale * outv[v];
#pragma unroll
            for (int j = 0; j < 5; ++j) {
                if (j < 4 || t < 128) {
                    int r = t + 256 * j;
                    const float* wr = rwc + (size_t)r * 128;
                    float d = 0.f;
#pragma unroll
                    for (int i = 0; i < 8; ++i) {
                        float u = 0.f;
#pragma unroll
                        for (int v4 = 0; v4 < 4; ++v4) {
                            float4 w4 = *(const float4*)&wr[i * 16 + v4 * 4];
                            u = fmaf(w4.x, ov[v4 * 4 + 0], u);
                            u = fmaf(w4.y, ov[v4 * 4 + 1], u);
                            u = fmaf(w4.z, ov[v4 * 4 + 2], u);
                            u = fmaf(w4.w, ov[v4 * 4 + 3], u);
                        }
                        d = fmaf(p_loc[j][i], u, d);
                    }
                    l_loc[j] += d;
                }
            }
            __syncthreads();
        }
    }
}

// ------------------------- class softmax + argmax mask ----------------------
__global__ void __launch_bounds__(256) mask_kernel(
    const float* __restrict__ caps, float* __restrict__ cls_out,
    float* __restrict__ masked)
{
    int b = blockIdx.x * 256 + threadIdx.x;
    if (b < 1024) {
        const float* cb = caps + (size_t)b * 32;
        float n0 = 0.f, n1 = 0.f;
#pragma unroll
        for (int v = 0; v < 16; ++v) {
            n0 = fmaf(cb[v], cb[v], n0);
            n1 = fmaf(cb[16 + v], cb[16 + v], n1);
        }
        n0 = sqrtf(n0); n1 = sqrtf(n1);
        float mx = fmaxf(n0, n1);
        float e0 = expf(n0 - mx), e1 = expf(n1 - mx);
        float inv = 1.f / (e0 + e1);
        cls_out[b * 2 + 0] = e0 * inv;
        cls_out[b * 2 + 1] = e1 * inv;
        int cs = (n1 > n0) ? 1 : 0;
#pragma unroll
        for (int v = 0; v < 16; ++v) {
            masked[(size_t)b * 32 + v]      = (cs == 0) ? cb[v] : 0.f;
            masked[(size_t)b * 32 + 16 + v] = (cs == 1) ? cb[16 + v] : 0.f;
        }
    }
}

// ------------------------- decoder GEMM -------------------------------------
template<int ACT>
__global__ void __launch_bounds__(256) dense_gemm(
    const float* __restrict__ A, const float* __restrict__ Bw,
    const float* __restrict__ bias, float* __restrict__ out,
    int M, int N, int K)
{
    __shared__ __align__(16) float As[16][128];
    __shared__ __align__(16) float Bs[16][64];
    const int t  = threadIdx.x;
    const int m0 = blockIdx.x * 128, n0 = blockIdx.y * 64;
    const int tx = t & 15, ty = t >> 4;
    const int am = t >> 1;
    const int ak = (t & 1) * 8;
    const int nb = (t & 15) * 4, kb = t >> 4;

    float acc[8][4];
#pragma unroll
    for (int i = 0; i < 8; ++i)
#pragma unroll
        for (int j = 0; j < 4; ++j) acc[i][j] = 0.f;

    for (int k0i = 0; k0i < K; k0i += 16) {
        {
            const float* ap = A + (size_t)(m0 + am) * K + k0i + ak;
            float4 v0 = *(const float4*)ap;
            float4 v1 = *(const float4*)(ap + 4);
            As[ak + 0][am] = v0.x; As[ak + 1][am] = v0.y;
            As[ak + 2][am] = v0.z; As[ak + 3][am] = v0.w;
            As[ak + 4][am] = v1.x; As[ak + 5][am] = v1.y;
            As[ak + 6][am] = v1.z; As[ak + 7][am] = v1.w;
        }
        {
            int k = k0i + kb;
            int n = n0 + nb;
            float4 v4 = make_float4(0.f, 0.f, 0.f, 0.f);
            if (n + 3 < N) {
                v4 = *(const float4*)&Bw[(size_t)k * N + n];
            } else {
                float tmp[4] = {0.f, 0.f, 0.f, 0.f};
#pragma unroll
                for (int e = 0; e < 4; ++e)
                    if (n + e < N) tmp[e] = Bw[(size_t)k * N + n + e];
                v4 = make_float4(tmp[0], tmp[1], tmp[2], tmp[3]);
            }
            *(float4*)&Bs[kb][nb] = v4;
        }
        __syncthreads();
#pragma unroll
        for (int kk = 0; kk < 16; ++kk) {
            float4 a0 = *(const float4*)&As[kk][ty * 8];
            float4 a1 = *(const float4*)&As[kk][ty * 8 + 4];
            float4 b0 = *(const float4*)&Bs[kk][tx * 4];
            float av[8] = {a0.x, a0.y, a0.z, a0.w, a1.x, a1.y, a1.z, a1.w};
            float bv[4] = {b0.x, b0.y, b0.z, b0.w};
#pragma unroll
            for (int i = 0; i < 8; ++i)
#pragma unroll
                for (int j = 0; j < 4; ++j)
                    acc[i][j] = fmaf(av[i], bv[j], acc[i][j]);
        }
        __syncthreads();
    }
#pragma unroll
    for (int i = 0; i < 8; ++i) {
        int mm = m0 + ty * 8 + i;
#pragma unroll
        for (int j = 0; j < 4; ++j) {
            int n = n0 + tx * 4 + j;
            if (n < N) {
                float v = acc[i][j] + bias[n];
                v = (ACT == 0) ? fmaxf(v, 0.f) : 1.f / (1.f + expf(-v));
                out[(size_t)mm * N + n] = v;
            }
        }
    }
}

// ------------------------- host launcher ------------------------------------
extern "C" void kernel_launch(void* const* d_in, const int* in_sizes, int n_in,
                              void* d_out, int out_size, void* d_ws, size_t ws_size,
                              hipStream_t stream)
{
    const float* x       = (const float*)d_in[0];
    const float* conv1_w = (const float*)d_in[1];
    const float* conv1_b = (const float*)d_in[2];
    const float* prim_w  = (const float*)d_in[3];
    const float* prim_b  = (const float*)d_in[4];
    const float* route_w = (const float*)d_in[5];
    const float* dec_w1  = (const float*)d_in[6];
    const float* dec_b1  = (const float*)d_in[7];
    const float* dec_w2  = (const float*)d_in[8];
    const float* dec_b2  = (const float*)d_in[9];
    const float* dec_w3  = (const float*)d_in[10];
    const float* dec_b3  = (const float*)d_in[11];

    float* ws     = (float*)d_ws;
    float* wT1    = ws;                                   //   62208 f32
    f16*   whT    = (f16*)(ws + 62208);                   // 5308416 f16
    f16*   wlT    = (f16*)(ws + 62208 + 2654208);         // 5308416 f16
    float* p      = ws + 62208 + 2 * 2654208;             // 9437184 f32
    float* caps   = p + 9437184;
    float* masked = caps + 32768;
    float* d1     = masked + 32768;
    float* d2     = d1 + 524288;
    float* hfp    = d2 + 1048576;                         // hh + hl (f16)
    float* outF   = (float*)d_out;

    const size_t fixedf = 62208 + 2 * 2654208 + 9437184 + 32768 + 32768
                        + 524288 + 1048576;               // 16,446,208 floats
    int chunk = 128;
    const int cand[3] = {512, 256, 128};
    for (int i = 0; i < 3; ++i) {
        if ((fixedf + (size_t)cand[i] * 102400ull) * sizeof(float) <= ws_size) {
            chunk = cand[i];
            break;
        }
    }
    f16* hh = (f16*)hfp;
    f16* hl = hh + (size_t)chunk * 102400;                // chunk*400*256 halves

    transpose_plain<<<dim3(4, 4), 256, 0, stream>>>(conv1_w, wT1, 256, 243);
    transpose_split_w<<<dim3(256, 4), 256, 0, stream>>>(prim_w, whT, wlT);

    const int nchunks = 1024 / chunk;
    for (int ci = 0; ci < nchunks; ++ci) {
        const float* xin = x + (size_t)ci * chunk * 2352;
        conv1_gemm<<<dim3(chunk * 400 / 64), 256, 0, stream>>>(
            xin, wT1, conv1_b, hh, hl);
        prim_mfma<<<dim3(chunk * 36 / 64, 4), 256, 0, stream>>>(
            hh, hl, whT, wlT, prim_b, p, ci * chunk);
    }

    routing_kernel<<<dim3(1024, 2), 256, 0, stream>>>(p, route_w, caps);
    mask_kernel<<<4, 256, 0, stream>>>(caps, outF, masked);

    dense_gemm<0><<<dim3(8, 8),  256, 0, stream>>>(masked, dec_w1, dec_b1, d1, 1024, 512, 32);
    dense_gemm<0><<<dim3(8, 16), 256, 0, stream>>>(d1, dec_w2, dec_b2, d2, 1024, 1024, 512);
    dense_gemm<1><<<dim3(8, 13), 256, 0, stream>>>(d2, dec_w3, dec_b3, outF + 2048, 1024, 784, 1024);
}

// Round 4
// 3369.834 us; speedup vs baseline: 6.5213x; 1.2895x over previous
//
#include <hip/hip_runtime.h>
#include <hip/hip_bf16.h>
#include <cmath>
#include <cstdint>

// ---------------------------------------------------------------------------
// CapsuleNet forward. Round 4:
//   - conv1 via materialized im2col (fp16 hi/lo split, K pad 243->256) +
//     64x64 fp16-split MFMA GEMM (same verified structure as prim).
//   - routing rewritten: 384 thr/block, priors q[3][16] in REGISTERS computed
//     once; 3 routing iterations are pure ALU + reductions (no spills, no
//     route_w re-streaming).
//   - prim conv MFMA unchanged (round-3 verified).
// value = hi + lo*2^-11 (fp16, lo pre-scaled 2^11); C = acc_hh + 2^-11*acc_x.
// ---------------------------------------------------------------------------

typedef _Float16 f16;
typedef _Float16 f16x8 __attribute__((ext_vector_type(8)));
typedef float    f32x4 __attribute__((ext_vector_type(4)));

// ------------------------- conv1 weight split: [n][k], k = c*81+khw ---------
__global__ void __launch_bounds__(256) w1split(
    const float* __restrict__ w, f16* __restrict__ wh, f16* __restrict__ wl)
{
    int idx = blockIdx.x * 256 + threadIdx.x;       // 65536
    int n = idx >> 8, k = idx & 255;
    float v = (k < 243) ? w[n * 243 + k] : 0.f;
    f16 hi = (f16)v;
    wh[idx] = hi;
    wl[idx] = (f16)((v - (float)hi) * 2048.0f);
}

// ------------------------- prim weight: permute + fp16 split ----------------
// in : w[n][c*81+khw]  -> out: whT/wlT [n][khw*256+c]
__global__ void __launch_bounds__(256) transpose_split_w(
    const float* __restrict__ w, f16* __restrict__ whT, f16* __restrict__ wlT)
{
    __shared__ float tile[5184];                  // 64 c x 81 khw
    const int n  = blockIdx.x;                    // 0..255
    const int cq = blockIdx.y;                    // 0..3
    const int t  = threadIdx.x;
    const float* wr = w + (size_t)n * 20736 + cq * 5184;
    for (int i = t; i < 5184; i += 256) tile[i] = wr[i];
    __syncthreads();
    f16* oh = whT + (size_t)n * 20736 + cq * 64;
    f16* ol = wlT + (size_t)n * 20736 + cq * 64;
    for (int j = t; j < 5184; j += 256) {
        int khw = j >> 6, c = j & 63;
        float v  = tile[c * 81 + khw];
        f16 hi   = (f16)v;
        f16 lo   = (f16)((v - (float)hi) * 2048.0f);
        oh[khw * 256 + c] = hi;
        ol[khw * 256 + c] = lo;
    }
}

// ------------------------- im2col of x, fp16 split --------------------------
// out[m][k], m = b*400 + py*20 + px (b local to chunk), k = c*81+khw, pad 256.
__global__ void __launch_bounds__(256) im2col_split(
    const float* __restrict__ x, f16* __restrict__ xh, f16* __restrict__ xl)
{
    int idx = blockIdx.x * 256 + threadIdx.x;
    int g = idx & 31, m = idx >> 5;
    int bb = m / 400, pix = m - bb * 400;
    int py = pix / 20, px = pix - py * 20;
    const float* xb = x + (size_t)bb * 2352 + py * 28 + px;
    f16x8 vh, vl;
#pragma unroll
    for (int e = 0; e < 8; ++e) {
        int k = g * 8 + e;
        float v = 0.f;
        if (k < 243) {
            int cc = k / 81, khw = k - cc * 81;
            int ky = khw / 9, kx = khw - ky * 9;
            v = xb[cc * 784 + ky * 28 + kx];
        }
        f16 hi = (f16)v;
        vh[e] = hi;
        vl[e] = (f16)((v - (float)hi) * 2048.0f);
    }
    *(f16x8*)&xh[(size_t)m * 256 + g * 8] = vh;
    *(f16x8*)&xl[(size_t)m * 256 + g * 8] = vl;
}

// ------------------------- conv1: fp16-split MFMA GEMM ----------------------
// C[M=chunk*400, 256] = xcol[M,256] * W1[256,256]; bias+ReLU; out hh/hl NHWC.
__global__ void __launch_bounds__(256) conv1_mfma(
    const f16* __restrict__ xh, const f16* __restrict__ xl,
    const f16* __restrict__ wh, const f16* __restrict__ wl,
    const float* __restrict__ bias, f16* __restrict__ hh, f16* __restrict__ hl)
{
    __shared__ __align__(16) f16 Ah[4096], Al[4096], Bh[4096], Bl[4096];
    const int t  = threadIdx.x;
    const int m0 = blockIdx.x * 64;
    const int n0 = blockIdx.y * 64;

    const int sr = t >> 3;
    const int sg = t & 7;
    int abase[2], bbase[2], wofs[2];
#pragma unroll
    for (int pp = 0; pp < 2; ++pp) {
        abase[pp] = (m0 + pp * 32 + sr) * 256 + sg * 8;
        bbase[pp] = (n0 + pp * 32 + sr) * 256 + sg * 8;
        int r = pp * 32 + sr;
        wofs[pp] = r * 64 + ((sg ^ (r & 7)) * 8);
    }

    f16x8 rAh[2], rAl[2], rBh[2], rBl[2];
    auto stage = [&](int s) {
        int off = s * 64;
#pragma unroll
        for (int pp = 0; pp < 2; ++pp) {
            rAh[pp] = *(const f16x8*)&xh[abase[pp] + off];
            rAl[pp] = *(const f16x8*)&xl[abase[pp] + off];
            rBh[pp] = *(const f16x8*)&wh[bbase[pp] + off];
            rBl[pp] = *(const f16x8*)&wl[bbase[pp] + off];
        }
    };

    const int lane = t & 63;
    const int wv   = t >> 6;
    const int wm   = wv >> 1, wn = wv & 1;
    const int li   = lane & 15, lq = lane >> 4;

    f32x4 acc_h[2][2], acc_x[2][2];
#pragma unroll
    for (int i = 0; i < 2; ++i)
#pragma unroll
        for (int j = 0; j < 2; ++j) {
            acc_h[i][j] = (f32x4){0.f, 0.f, 0.f, 0.f};
            acc_x[i][j] = (f32x4){0.f, 0.f, 0.f, 0.f};
        }

    stage(0);

    for (int s = 0; s < 4; ++s) {
        __syncthreads();
#pragma unroll
        for (int pp = 0; pp < 2; ++pp) {
            *(f16x8*)&Ah[wofs[pp]] = rAh[pp];
            *(f16x8*)&Al[wofs[pp]] = rAl[pp];
            *(f16x8*)&Bh[wofs[pp]] = rBh[pp];
            *(f16x8*)&Bl[wofs[pp]] = rBl[pp];
        }
        __syncthreads();
        if (s + 1 < 4) stage(s + 1);
#pragma unroll
        for (int h = 0; h < 2; ++h) {
            int g = h * 4 + lq;
            f16x8 ah[2], al[2], bh[2], bl[2];
#pragma unroll
            for (int mf = 0; mf < 2; ++mf) {
                int r = wm * 32 + mf * 16 + li;
                int u = r * 64 + ((g ^ (r & 7)) * 8);
                ah[mf] = *(const f16x8*)&Ah[u];
                al[mf] = *(const f16x8*)&Al[u];
            }
#pragma unroll
            for (int nf = 0; nf < 2; ++nf) {
                int r = wn * 32 + nf * 16 + li;
                int u = r * 64 + ((g ^ (r & 7)) * 8);
                bh[nf] = *(const f16x8*)&Bh[u];
                bl[nf] = *(const f16x8*)&Bl[u];
            }
#pragma unroll
            for (int mf = 0; mf < 2; ++mf)
#pragma unroll
                for (int nf = 0; nf < 2; ++nf) {
                    acc_h[mf][nf] = __builtin_amdgcn_mfma_f32_16x16x32_f16(
                        ah[mf], bh[nf], acc_h[mf][nf], 0, 0, 0);
                    acc_x[mf][nf] = __builtin_amdgcn_mfma_f32_16x16x32_f16(
                        ah[mf], bl[nf], acc_x[mf][nf], 0, 0, 0);
                    acc_x[mf][nf] = __builtin_amdgcn_mfma_f32_16x16x32_f16(
                        al[mf], bh[nf], acc_x[mf][nf], 0, 0, 0);
                }
        }
    }

    float bn[2];
    bn[0] = bias[n0 + wn * 32 + li];
    bn[1] = bias[n0 + wn * 32 + 16 + li];
#pragma unroll
    for (int mf = 0; mf < 2; ++mf) {
        int mb = m0 + wm * 32 + mf * 16 + lq * 4;
#pragma unroll
        for (int r = 0; r < 4; ++r) {
            size_t row = (size_t)(mb + r) * 256;
#pragma unroll
            for (int nf = 0; nf < 2; ++nf) {
                int n   = n0 + wn * 32 + nf * 16 + li;
                float v = acc_h[mf][nf][r]
                        + acc_x[mf][nf][r] * (1.0f / 2048.0f) + bn[nf];
                v = fmaxf(v, 0.f);
                f16 hi = (f16)v;
                hh[row + n] = hi;
                hl[row + n] = (f16)((v - (float)hi) * 2048.0f);
            }
        }
    }
}

// ------------------------- prim conv: fp16-split MFMA (round-3 verified) ----
__global__ void __launch_bounds__(256) prim_mfma(
    const f16* __restrict__ hh, const f16* __restrict__ hl,
    const f16* __restrict__ whT, const f16* __restrict__ wlT,
    const float* __restrict__ bias, float* __restrict__ p, int b_base)
{
    __shared__ __align__(16) f16 Ah[4096], Al[4096], Bh[4096], Bl[4096];
    const int t  = threadIdx.x;
    const int m0 = blockIdx.x * 64;
    const int n0 = blockIdx.y * 64;

    const int sr = t >> 3;
    const int sg = t & 7;
    int abase[2], bbase[2], wofs[2];
#pragma unroll
    for (int pp = 0; pp < 2; ++pp) {
        int m  = m0 + pp * 32 + sr;
        int bb = m / 36, pix = m - bb * 36;
        int py = pix / 6, px = pix - py * 6;
        abase[pp] = ((bb * 400 + py * 40 + px * 2) << 8) + sg * 8;
        bbase[pp] = (n0 + pp * 32 + sr) * 20736 + sg * 8;
        int r = pp * 32 + sr;
        wofs[pp] = r * 64 + ((sg ^ (r & 7)) * 8);
    }

    f16x8 rAh[2], rAl[2], rBh[2], rBl[2];
    auto stage = [&](int s) {
        int khw = s >> 2;
        int ky = khw / 9, kx = khw - ky * 9;
        int aoff = (ky * 20 + kx) * 256 + (s & 3) * 64;
        int boff = s * 64;
#pragma unroll
        for (int pp = 0; pp < 2; ++pp) {
            rAh[pp] = *(const f16x8*)&hh[abase[pp] + aoff];
            rAl[pp] = *(const f16x8*)&hl[abase[pp] + aoff];
            rBh[pp] = *(const f16x8*)&whT[bbase[pp] + boff];
            rBl[pp] = *(const f16x8*)&wlT[bbase[pp] + boff];
        }
    };

    const int lane = t & 63;
    const int wv   = t >> 6;
    const int wm   = wv >> 1, wn = wv & 1;
    const int li   = lane & 15, lq = lane >> 4;

    f32x4 acc_h[2][2], acc_x[2][2];
#pragma unroll
    for (int i = 0; i < 2; ++i)
#pragma unroll
        for (int j = 0; j < 2; ++j) {
            acc_h[i][j] = (f32x4){0.f, 0.f, 0.f, 0.f};
            acc_x[i][j] = (f32x4){0.f, 0.f, 0.f, 0.f};
        }

    stage(0);

    for (int s = 0; s < 324; ++s) {
        __syncthreads();
#pragma unroll
        for (int pp = 0; pp < 2; ++pp) {
            *(f16x8*)&Ah[wofs[pp]] = rAh[pp];
            *(f16x8*)&Al[wofs[pp]] = rAl[pp];
            *(f16x8*)&Bh[wofs[pp]] = rBh[pp];
            *(f16x8*)&Bl[wofs[pp]] = rBl[pp];
        }
        __syncthreads();
        if (s + 1 < 324) stage(s + 1);
#pragma unroll
        for (int h = 0; h < 2; ++h) {
            int g = h * 4 + lq;
            f16x8 ah[2], al[2], bh[2], bl[2];
#pragma unroll
            for (int mf = 0; mf < 2; ++mf) {
                int r = wm * 32 + mf * 16 + li;
                int u = r * 64 + ((g ^ (r & 7)) * 8);
                ah[mf] = *(const f16x8*)&Ah[u];
                al[mf] = *(const f16x8*)&Al[u];
            }
#pragma unroll
            for (int nf = 0; nf < 2; ++nf) {
                int r = wn * 32 + nf * 16 + li;
                int u = r * 64 + ((g ^ (r & 7)) * 8);
                bh[nf] = *(const f16x8*)&Bh[u];
                bl[nf] = *(const f16x8*)&Bl[u];
            }
#pragma unroll
            for (int mf = 0; mf < 2; ++mf)
#pragma unroll
                for (int nf = 0; nf < 2; ++nf) {
                    acc_h[mf][nf] = __builtin_amdgcn_mfma_f32_16x16x32_f16(
                        ah[mf], bh[nf], acc_h[mf][nf], 0, 0, 0);
                    acc_x[mf][nf] = __builtin_amdgcn_mfma_f32_16x16x32_f16(
                        ah[mf], bl[nf], acc_x[mf][nf], 0, 0, 0);
                    acc_x[mf][nf] = __builtin_amdgcn_mfma_f32_16x16x32_f16(
                        al[mf], bh[nf], acc_x[mf][nf], 0, 0, 0);
                }
        }
    }

    float bn[2];
    bn[0] = bias[n0 + wn * 32 + li];
    bn[1] = bias[n0 + wn * 32 + 16 + li];
#pragma unroll
    for (int mf = 0; mf < 2; ++mf) {
        int mb = m0 + wm * 32 + mf * 16 + lq * 4;
#pragma unroll
        for (int r = 0; r < 4; ++r) {
            int m  = mb + r;
            int bb = m / 36, pix = m - bb * 36;
            size_t rowp = (size_t)(b_base + bb) * 9216 + pix * 8;
#pragma unroll
            for (int nf = 0; nf < 2; ++nf) {
                int n   = n0 + wn * 32 + nf * 16 + li;
                int cap = n >> 3, vec = n & 7;
                float v = acc_h[mf][nf][r]
                        + acc_x[mf][nf][r] * (1.0f / 2048.0f) + bn[nf];
                p[rowp + cap * 288 + vec] = v;
            }
        }
    }
}

// ------------------------- dynamic routing (register-priors) ----------------
// grid (1024, 2), 384 threads. Each thread owns routes r = t + 384*j, j<3.
// Phase 1: q[j][v] = sum_i p[b,r,i]*rw[c,r,i,v] (one sweep). Iterations are
// pure register ALU + shuffle/LDS reductions.
__global__ void __launch_bounds__(384) routing2(
    const float* __restrict__ p, const float* __restrict__ rw,
    float* __restrict__ caps)
{
    const int b = blockIdx.x;
    const int c = blockIdx.y;
    const int t = threadIdx.x;
    const int lane = t & 63, wid = t >> 6;        // wid 0..5
    __shared__ float redbuf[6];
    __shared__ float tred[6][16];
    __shared__ float outv[16];

    const float* pb  = p  + (size_t)b * 9216;
    const float* rwc = rw + (size_t)c * 147456;

    float q[3][16];
    float l[3] = {0.f, 0.f, 0.f};

#pragma unroll
    for (int j = 0; j < 3; ++j) {
        int r = t + 384 * j;
        float4 p0 = *(const float4*)&pb[r * 8];
        float4 p1 = *(const float4*)&pb[r * 8 + 4];
        float pr[8] = {p0.x, p0.y, p0.z, p0.w, p1.x, p1.y, p1.z, p1.w};
#pragma unroll
        for (int v = 0; v < 16; ++v) q[j][v] = 0.f;
        const float* wr = rwc + (size_t)r * 128;
#pragma unroll
        for (int i = 0; i < 8; ++i) {
#pragma unroll
            for (int v4 = 0; v4 < 4; ++v4) {
                float4 w4 = *(const float4*)&wr[i * 16 + v4 * 4];
                q[j][v4 * 4 + 0] = fmaf(pr[i], w4.x, q[j][v4 * 4 + 0]);
                q[j][v4 * 4 + 1] = fmaf(pr[i], w4.y, q[j][v4 * 4 + 1]);
                q[j][v4 * 4 + 2] = fmaf(pr[i], w4.z, q[j][v4 * 4 + 2]);
                q[j][v4 * 4 + 3] = fmaf(pr[i], w4.w, q[j][v4 * 4 + 3]);
            }
        }
    }

    for (int it = 0; it < 3; ++it) {
        // softmax over all 1152 logits (same value broadcast over v)
        float lm = fmaxf(fmaxf(l[0], l[1]), l[2]);
#pragma unroll
        for (int off = 32; off; off >>= 1) lm = fmaxf(lm, __shfl_down(lm, off, 64));
        __syncthreads();
        if (lane == 0) redbuf[wid] = lm;
        __syncthreads();
        lm = fmaxf(fmaxf(fmaxf(redbuf[0], redbuf[1]), fmaxf(redbuf[2], redbuf[3])),
                   fmaxf(redbuf[4], redbuf[5]));

        float e[3];
        float ls = 0.f;
#pragma unroll
        for (int j = 0; j < 3; ++j) { e[j] = __expf(l[j] - lm); ls += e[j]; }
#pragma unroll
        for (int off = 32; off; off >>= 1) ls += __shfl_down(ls, off, 64);
        __syncthreads();
        if (lane == 0) redbuf[wid] = ls;
        __syncthreads();
        ls = redbuf[0] + redbuf[1] + redbuf[2] + redbuf[3] + redbuf[4] + redbuf[5];
        const float inv = 1.f / ls;

        // pass A: tv[v] = sum_j e[j]*q[j][v]   (pure registers)
        float tv[16];
#pragma unroll
        for (int v = 0; v < 16; ++v)
            tv[v] = fmaf(e[0], q[0][v], fmaf(e[1], q[1][v], e[2] * q[2][v]));
#pragma unroll
        for (int v = 0; v < 16; ++v) {
            float xv = tv[v];
#pragma unroll
            for (int off = 32; off; off >>= 1) xv += __shfl_down(xv, off, 64);
            tv[v] = xv;
        }
        __syncthreads();
        if (lane == 0) {
#pragma unroll
            for (int v = 0; v < 16; ++v) tred[wid][v] = tv[v];
        }
        __syncthreads();
        if (t < 16)
            outv[t] = (tred[0][t] + tred[1][t] + tred[2][t]
                     + tred[3][t] + tred[4][t] + tred[5][t]) * inv;
        __syncthreads();

        float s2 = 0.f;
#pragma unroll
        for (int v = 0; v < 16; ++v) s2 += outv[v] * outv[v];
        const float scale = s2 / ((1.f + s2) * sqrtf(s2));

        if (it == 2) {
            if (t < 16) caps[((size_t)b * 2 + c) * 16 + t] = scale * outv[t];
        } else {
            float ov[16];
#pragma unroll
            for (int v = 0; v < 16; ++v) ov[v] = scale * outv[v];
            // pass B: l[j] += sum_v q[j][v]*ov[v]   (pure registers)
#pragma unroll
            for (int j = 0; j < 3; ++j) {
                float d = 0.f;
#pragma unroll
                for (int v = 0; v < 16; ++v) d = fmaf(q[j][v], ov[v], d);
                l[j] += d;
            }
        }
    }
}

// ------------------------- class softmax + argmax mask ----------------------
__global__ void __launch_bounds__(256) mask_kernel(
    const float* __restrict__ caps, float* __restrict__ cls_out,
    float* __restrict__ masked)
{
    int b = blockIdx.x * 256 + threadIdx.x;
    if (b < 1024) {
        const float* cb = caps + (size_t)b * 32;
        float n0 = 0.f, n1 = 0.f;
#pragma unroll
        for (int v = 0; v < 16; ++v) {
            n0 = fmaf(cb[v], cb[v], n0);
            n1 = fmaf(cb[16 + v], cb[16 + v], n1);
        }
        n0 = sqrtf(n0); n1 = sqrtf(n1);
        float mx = fmaxf(n0, n1);
        float e0 = expf(n0 - mx), e1 = expf(n1 - mx);
        float inv = 1.f / (e0 + e1);
        cls_out[b * 2 + 0] = e0 * inv;
        cls_out[b * 2 + 1] = e1 * inv;
        int cs = (n1 > n0) ? 1 : 0;
#pragma unroll
        for (int v = 0; v < 16; ++v) {
            masked[(size_t)b * 32 + v]      = (cs == 0) ? cb[v] : 0.f;
            masked[(size_t)b * 32 + 16 + v] = (cs == 1) ? cb[16 + v] : 0.f;
        }
    }
}

// ------------------------- decoder GEMM -------------------------------------
template<int ACT>
__global__ void __launch_bounds__(256) dense_gemm(
    const float* __restrict__ A, const float* __restrict__ Bw,
    const float* __restrict__ bias, float* __restrict__ out,
    int M, int N, int K)
{
    __shared__ __align__(16) float As[16][128];
    __shared__ __align__(16) float Bs[16][64];
    const int t  = threadIdx.x;
    const int m0 = blockIdx.x * 128, n0 = blockIdx.y * 64;
    const int tx = t & 15, ty = t >> 4;
    const int am = t >> 1;
    const int ak = (t & 1) * 8;
    const int nb = (t & 15) * 4, kb = t >> 4;

    float acc[8][4];
#pragma unroll
    for (int i = 0; i < 8; ++i)
#pragma unroll
        for (int j = 0; j < 4; ++j) acc[i][j] = 0.f;

    for (int k0i = 0; k0i < K; k0i += 16) {
        {
            const float* ap = A + (size_t)(m0 + am) * K + k0i + ak;
            float4 v0 = *(const float4*)ap;
            float4 v1 = *(const float4*)(ap + 4);
            As[ak + 0][am] = v0.x; As[ak + 1][am] = v0.y;
            As[ak + 2][am] = v0.z; As[ak + 3][am] = v0.w;
            As[ak + 4][am] = v1.x; As[ak + 5][am] = v1.y;
            As[ak + 6][am] = v1.z; As[ak + 7][am] = v1.w;
        }
        {
            int k = k0i + kb;
            int n = n0 + nb;
            float4 v4 = make_float4(0.f, 0.f, 0.f, 0.f);
            if (n + 3 < N) {
                v4 = *(const float4*)&Bw[(size_t)k * N + n];
            } else {
                float tmp[4] = {0.f, 0.f, 0.f, 0.f};
#pragma unroll
                for (int e = 0; e < 4; ++e)
                    if (n + e < N) tmp[e] = Bw[(size_t)k * N + n + e];
                v4 = make_float4(tmp[0], tmp[1], tmp[2], tmp[3]);
            }
            *(float4*)&Bs[kb][nb] = v4;
        }
        __syncthreads();
#pragma unroll
        for (int kk = 0; kk < 16; ++kk) {
            float4 a0 = *(const float4*)&As[kk][ty * 8];
            float4 a1 = *(const float4*)&As[kk][ty * 8 + 4];
            float4 b0 = *(const float4*)&Bs[kk][tx * 4];
            float av[8] = {a0.x, a0.y, a0.z, a0.w, a1.x, a1.y, a1.z, a1.w};
            float bv[4] = {b0.x, b0.y, b0.z, b0.w};
#pragma unroll
            for (int i = 0; i < 8; ++i)
#pragma unroll
                for (int j = 0; j < 4; ++j)
                    acc[i][j] = fmaf(av[i], bv[j], acc[i][j]);
        }
        __syncthreads();
    }
#pragma unroll
    for (int i = 0; i < 8; ++i) {
        int mm = m0 + ty * 8 + i;
#pragma unroll
        for (int j = 0; j < 4; ++j) {
            int n = n0 + tx * 4 + j;
            if (n < N) {
                float v = acc[i][j] + bias[n];
                v = (ACT == 0) ? fmaxf(v, 0.f) : 1.f / (1.f + expf(-v));
                out[(size_t)mm * N + n] = v;
            }
        }
    }
}

// ------------------------- host launcher ------------------------------------
extern "C" void kernel_launch(void* const* d_in, const int* in_sizes, int n_in,
                              void* d_out, int out_size, void* d_ws, size_t ws_size,
                              hipStream_t stream)
{
    const float* x       = (const float*)d_in[0];
    const float* conv1_w = (const float*)d_in[1];
    const float* conv1_b = (const float*)d_in[2];
    const float* prim_w  = (const float*)d_in[3];
    const float* prim_b  = (const float*)d_in[4];
    const float* route_w = (const float*)d_in[5];
    const float* dec_w1  = (const float*)d_in[6];
    const float* dec_b1  = (const float*)d_in[7];
    const float* dec_w2  = (const float*)d_in[8];
    const float* dec_b2  = (const float*)d_in[9];
    const float* dec_w3  = (const float*)d_in[10];
    const float* dec_b3  = (const float*)d_in[11];

    f16*   whT1 = (f16*)d_ws;                       //   65536 halves
    f16*   wlT1 = whT1 + 65536;
    f16*   whT  = wlT1 + 65536;                     // 5308416 halves
    f16*   wlT  = whT + 5308416;
    float* pbuf   = (float*)(wlT + 5308416);        // 9437184 f32
    float* caps   = pbuf + 9437184;
    float* masked = caps + 32768;
    float* d1     = masked + 32768;
    float* d2     = d1 + 524288;
    f16*   chunkbase = (f16*)(d2 + 1048576);
    float* outF   = (float*)d_out;

    const size_t fixed_bytes = 65798144ull;         // everything above chunkbase
    int chunk = 128;
    const int cand[4] = {1024, 512, 256, 128};
    for (int i = 0; i < 4; ++i) {
        if (fixed_bytes + (size_t)cand[i] * 819200ull <= ws_size) {
            chunk = cand[i];
            break;
        }
    }
    f16* xch = chunkbase;
    f16* xcl = xch + (size_t)chunk * 102400;
    f16* hh  = xcl + (size_t)chunk * 102400;
    f16* hl  = hh  + (size_t)chunk * 102400;

    w1split<<<256, 256, 0, stream>>>(conv1_w, whT1, wlT1);
    transpose_split_w<<<dim3(256, 4), 256, 0, stream>>>(prim_w, whT, wlT);

    const int nchunks = 1024 / chunk;
    for (int ci = 0; ci < nchunks; ++ci) {
        const float* xin = x + (size_t)ci * chunk * 2352;
        im2col_split<<<chunk * 50, 256, 0, stream>>>(xin, xch, xcl);
        conv1_mfma<<<dim3(chunk * 400 / 64, 4), 256, 0, stream>>>(
            xch, xcl, whT1, wlT1, conv1_b, hh, hl);
        prim_mfma<<<dim3(chunk * 36 / 64, 4), 256, 0, stream>>>(
            hh, hl, whT, wlT, prim_b, pbuf, ci * chunk);
    }

    routing2<<<dim3(1024, 2), 384, 0, stream>>>(pbuf, route_w, caps);
    mask_kernel<<<4, 256, 0, stream>>>(caps, outF, masked);

    dense_gemm<0><<<dim3(8, 8),  256, 0, stream>>>(masked, dec_w1, dec_b1, d1, 1024, 512, 32);
    dense_gemm<0><<<dim3(8, 16), 256, 0, stream>>>(d1, dec_w2, dec_b2, d2, 1024, 1024, 512);
    dense_gemm<1><<<dim3(8, 13), 256, 0, stream>>>(d2, dec_w3, dec_b3, outF + 2048, 1024, 784, 1024);
}

// Round 5
// 2581.251 us; speedup vs baseline: 8.5135x; 1.3055x over previous
//
#include <hip/hip_runtime.h>
#include <hip/hip_bf16.h>
#include <cmath>
#include <cstdint>

// ---------------------------------------------------------------------------
// CapsuleNet forward. Round 5:
//   - conv1: fused im2col (gather x + fp16 hi/lo split in staging) ->
//     64x64 16x16x32-MFMA GEMM (r3/r4-verified core). No xcol buffers ->
//     chunk=256 fits the workspace.
//   - prim: 128x128 block, 2x2 waves of 64x64, mfma_f32_32x32x16_f16
//     (2x less LDS traffic per FLOP), split-K x4 over channel quarters
//     (576 blocks), global_load_lds staging (no prefetch VGPRs),
//     atomicAdd epilogue into zeroed p.
// value = hi + lo*2^-11 (f16, lo pre-scaled 2^11); C = acc_hh + 2^-11*acc_x.
// ---------------------------------------------------------------------------

typedef _Float16 f16;
typedef _Float16 f16x8 __attribute__((ext_vector_type(8)));
typedef float    f32x4 __attribute__((ext_vector_type(4)));
typedef float    f32x16 __attribute__((ext_vector_type(16)));

__device__ __forceinline__ void dma16(const f16* g, f16* l)
{
    __builtin_amdgcn_global_load_lds(
        (const __attribute__((address_space(1))) void*)g,
        (__attribute__((address_space(3))) void*)l, 16, 0, 0);
}

// ------------------------- conv1 weight split: [n][k], k = c*81+khw ---------
__global__ void __launch_bounds__(256) w1split(
    const float* __restrict__ w, f16* __restrict__ wh, f16* __restrict__ wl)
{
    int idx = blockIdx.x * 256 + threadIdx.x;       // 65536
    int n = idx >> 8, k = idx & 255;
    float v = (k < 243) ? w[n * 243 + k] : 0.f;
    f16 hi = (f16)v;
    wh[idx] = hi;
    wl[idx] = (f16)((v - (float)hi) * 2048.0f);
}

// ------------------------- prim weight: permute + fp16 split ----------------
// in : w[n][c*81+khw]  -> out: whT/wlT [n][khw*256+c]  (vectorized 16B stores)
__global__ void __launch_bounds__(256) transpose_split_w(
    const float* __restrict__ w, f16* __restrict__ whT, f16* __restrict__ wlT)
{
    __shared__ float tile[5184];                  // 64 c x 81 khw
    const int n  = blockIdx.x;                    // 0..255
    const int cq = blockIdx.y;                    // 0..3
    const int t  = threadIdx.x;
    const float* wr = w + (size_t)n * 20736 + cq * 5184;
    for (int i = t; i < 5184; i += 256) tile[i] = wr[i];
    __syncthreads();
    f16* oh = whT + (size_t)n * 20736 + cq * 64;
    f16* ol = wlT + (size_t)n * 20736 + cq * 64;
    for (int idx = t; idx < 648; idx += 256) {    // 81 khw x 8 c-groups
        int khw = idx >> 3, cg = idx & 7;
        f16x8 vh, vl;
#pragma unroll
        for (int e = 0; e < 8; ++e) {
            float v = tile[(cg * 8 + e) * 81 + khw];
            f16 hi  = (f16)v;
            vh[e] = hi;
            vl[e] = (f16)((v - (float)hi) * 2048.0f);
        }
        *(f16x8*)&oh[khw * 256 + cg * 8] = vh;
        *(f16x8*)&ol[khw * 256 + cg * 8] = vl;
    }
}

// ------------------------- conv1: fused im2col + fp16-split MFMA ------------
// C[M=chunk*400, 256] = im2col(x)[M,256] * W1[256,256]; bias+ReLU; hh/hl NHWC.
__global__ void __launch_bounds__(256) conv1_mfma(
    const float* __restrict__ x,
    const f16* __restrict__ wh, const f16* __restrict__ wl,
    const float* __restrict__ bias, f16* __restrict__ hh, f16* __restrict__ hl)
{
    __shared__ __align__(16) f16 Ah[4096], Al[4096], Bh[4096], Bl[4096];
    __shared__ int otab[256];
    const int t  = threadIdx.x;
    const int m0 = blockIdx.x * 64;
    const int n0 = blockIdx.y * 64;

    {   // otab: k -> x offset (c*784 + ky*28 + kx), -1 pads
        int k = t;
        int off = -1;
        if (k < 243) {
            int c = k / 81, khw = k - c * 81;
            int ky = khw / 9, kx = khw - ky * 9;
            off = c * 784 + ky * 28 + kx;
        }
        otab[t] = off;
    }

    const int sr = t >> 3;
    const int sg = t & 7;
    const float* xb[2];
    int bbase[2], wofs[2];
#pragma unroll
    for (int pp = 0; pp < 2; ++pp) {
        int r = pp * 32 + sr;
        int m = m0 + r;
        int bb = m / 400, pix = m - bb * 400;
        int py = pix / 20, px = pix - py * 20;
        xb[pp] = x + (size_t)bb * 2352 + py * 28 + px;
        bbase[pp] = (n0 + r) * 256 + sg * 8;
        wofs[pp] = r * 64 + ((sg ^ (r & 7)) * 8);
    }

    float rx[2][8];
    f16x8 rBh[2], rBl[2];
    __syncthreads();                              // otab ready
    auto stage = [&](int s) {
#pragma unroll
        for (int pp = 0; pp < 2; ++pp) {
#pragma unroll
            for (int e = 0; e < 8; ++e) {
                int off = otab[s * 64 + sg * 8 + e];
                rx[pp][e] = (off >= 0) ? xb[pp][off] : 0.f;
            }
            rBh[pp] = *(const f16x8*)&wh[bbase[pp] + s * 64];
            rBl[pp] = *(const f16x8*)&wl[bbase[pp] + s * 64];
        }
    };

    const int lane = t & 63;
    const int wv   = t >> 6;
    const int wm   = wv >> 1, wn = wv & 1;
    const int li   = lane & 15, lq = lane >> 4;

    f32x4 acc_h[2][2], acc_x[2][2];
#pragma unroll
    for (int i = 0; i < 2; ++i)
#pragma unroll
        for (int j = 0; j < 2; ++j) {
            acc_h[i][j] = (f32x4){0.f, 0.f, 0.f, 0.f};
            acc_x[i][j] = (f32x4){0.f, 0.f, 0.f, 0.f};
        }

    stage(0);

    for (int s = 0; s < 4; ++s) {
        __syncthreads();
#pragma unroll
        for (int pp = 0; pp < 2; ++pp) {
            f16x8 vh, vl;
#pragma unroll
            for (int e = 0; e < 8; ++e) {
                float v = rx[pp][e];
                f16 hi = (f16)v;
                vh[e] = hi;
                vl[e] = (f16)((v - (float)hi) * 2048.0f);
            }
            *(f16x8*)&Ah[wofs[pp]] = vh;
            *(f16x8*)&Al[wofs[pp]] = vl;
            *(f16x8*)&Bh[wofs[pp]] = rBh[pp];
            *(f16x8*)&Bl[wofs[pp]] = rBl[pp];
        }
        __syncthreads();
        if (s + 1 < 4) stage(s + 1);
#pragma unroll
        for (int h = 0; h < 2; ++h) {
            int g = h * 4 + lq;
            f16x8 ah[2], al[2], bh[2], bl[2];
#pragma unroll
            for (int mf = 0; mf < 2; ++mf) {
                int r = wm * 32 + mf * 16 + li;
                int u = r * 64 + ((g ^ (r & 7)) * 8);
                ah[mf] = *(const f16x8*)&Ah[u];
                al[mf] = *(const f16x8*)&Al[u];
            }
#pragma unroll
            for (int nf = 0; nf < 2; ++nf) {
                int r = wn * 32 + nf * 16 + li;
                int u = r * 64 + ((g ^ (r & 7)) * 8);
                bh[nf] = *(const f16x8*)&Bh[u];
                bl[nf] = *(const f16x8*)&Bl[u];
            }
#pragma unroll
            for (int mf = 0; mf < 2; ++mf)
#pragma unroll
                for (int nf = 0; nf < 2; ++nf) {
                    acc_h[mf][nf] = __builtin_amdgcn_mfma_f32_16x16x32_f16(
                        ah[mf], bh[nf], acc_h[mf][nf], 0, 0, 0);
                    acc_x[mf][nf] = __builtin_amdgcn_mfma_f32_16x16x32_f16(
                        ah[mf], bl[nf], acc_x[mf][nf], 0, 0, 0);
                    acc_x[mf][nf] = __builtin_amdgcn_mfma_f32_16x16x32_f16(
                        al[mf], bh[nf], acc_x[mf][nf], 0, 0, 0);
                }
        }
    }

    float bn[2];
    bn[0] = bias[n0 + wn * 32 + li];
    bn[1] = bias[n0 + wn * 32 + 16 + li];
#pragma unroll
    for (int mf = 0; mf < 2; ++mf) {
        int mb = m0 + wm * 32 + mf * 16 + lq * 4;
#pragma unroll
        for (int r = 0; r < 4; ++r) {
            size_t row = (size_t)(mb + r) * 256;
#pragma unroll
            for (int nf = 0; nf < 2; ++nf) {
                int n   = n0 + wn * 32 + nf * 16 + li;
                float v = acc_h[mf][nf][r]
                        + acc_x[mf][nf][r] * (1.0f / 2048.0f) + bn[nf];
                v = fmaxf(v, 0.f);
                f16 hi = (f16)v;
                hh[row + n] = hi;
                hl[row + n] = (f16)((v - (float)hi) * 2048.0f);
            }
        }
    }
}

// ------------------------- prim conv: 32x32x16 MFMA, split-K4, DMA ----------
// GEMM: C[M=chunk*36, 256] += im2col(h)[M, Kq] * W[Kq, 256], Kq = 81*64 (kz).
// Block 128x128, waves 2x2 (64x64 each). LDS XOR swizzle row*64+((g^(r&7))*8);
// global_load_lds lane map: lane l=(j*8+q) loads (row R+j, group q^j) ->
// lands at uniform base + l*16B == swizzled slot (R mult of 8).
__global__ void __launch_bounds__(256, 2) prim_mfma32(
    const f16* __restrict__ hh, const f16* __restrict__ hl,
    const f16* __restrict__ whT, const f16* __restrict__ wlT,
    const float* __restrict__ bias, float* __restrict__ p, int b_base)
{
    __shared__ __align__(16) f16 Ah[8192], Al[8192], Bh[8192], Bl[8192];
    const int t    = threadIdx.x;
    const int m0   = blockIdx.x * 128;
    const int n0   = blockIdx.y * 128;
    const int kz64 = blockIdx.z * 64;

    const int l  = t & 63, wv = t >> 6;
    const int wm = wv >> 1, wn = wv & 1;
    const int lr = l & 31, lh = l >> 5;

    // DMA coords
    const int dj = l >> 3, dq = l & 7, dg = dq ^ dj;
    int aoff[4], boff[4];
#pragma unroll
    for (int i = 0; i < 4; ++i) {
        int r  = wv * 32 + i * 8 + dj;
        int m  = m0 + r;
        int bb = m / 36, pix = m - bb * 36;
        int py = pix / 6, px = pix - py * 6;
        aoff[i] = (bb * 400 + py * 40 + px * 2) * 256 + kz64 + dg * 8;
        boff[i] = (n0 + r) * 20736 + kz64 + dg * 8;
    }

    f32x16 acc_h[2][2], acc_x[2][2];
#pragma unroll
    for (int i = 0; i < 2; ++i)
#pragma unroll
        for (int j = 0; j < 2; ++j) {
#pragma unroll
            for (int e = 0; e < 16; ++e) { acc_h[i][j][e] = 0.f; acc_x[i][j][e] = 0.f; }
        }

    for (int s = 0; s < 81; ++s) {
        int ky = s / 9, kx = s - ky * 9;
        int aAdd = (ky * 20 + kx) * 256;
        int bAdd = s * 256;
#pragma unroll
        for (int i = 0; i < 4; ++i) {
            int lb = (wv * 32 + i * 8) * 64;      // wave-uniform LDS base
            dma16(hh  + aoff[i] + aAdd, &Ah[lb]);
            dma16(hl  + aoff[i] + aAdd, &Al[lb]);
            dma16(whT + boff[i] + bAdd, &Bh[lb]);
            dma16(wlT + boff[i] + bAdd, &Bl[lb]);
        }
        __syncthreads();                          // drains DMA (vmcnt) + all waves
#pragma unroll
        for (int h = 0; h < 4; ++h) {
            int gg = 2 * h + lh;
            f16x8 ah[2], al[2], bh[2], bl[2];
#pragma unroll
            for (int mf = 0; mf < 2; ++mf) {
                int r = wm * 64 + mf * 32 + lr;
                int u = r * 64 + ((gg ^ (r & 7)) * 8);
                ah[mf] = *(const f16x8*)&Ah[u];
                al[mf] = *(const f16x8*)&Al[u];
            }
#pragma unroll
            for (int nf = 0; nf < 2; ++nf) {
                int r = wn * 64 + nf * 32 + lr;
                int u = r * 64 + ((gg ^ (r & 7)) * 8);
                bh[nf] = *(const f16x8*)&Bh[u];
                bl[nf] = *(const f16x8*)&Bl[u];
            }
#pragma unroll
            for (int mf = 0; mf < 2; ++mf)
#pragma unroll
                for (int nf = 0; nf < 2; ++nf) {
                    acc_h[mf][nf] = __builtin_amdgcn_mfma_f32_32x32x16_f16(
                        ah[mf], bh[nf], acc_h[mf][nf], 0, 0, 0);
                    acc_x[mf][nf] = __builtin_amdgcn_mfma_f32_32x32x16_f16(
                        ah[mf], bl[nf], acc_x[mf][nf], 0, 0, 0);
                    acc_x[mf][nf] = __builtin_amdgcn_mfma_f32_32x32x16_f16(
                        al[mf], bh[nf], acc_x[mf][nf], 0, 0, 0);
                }
        }
        __syncthreads();                          // reads done before next DMA
    }

    // epilogue: C/D 32x32 layout: col = lane&31, row = (reg&3)+8*(reg>>2)+4*lh
    float bn[2];
#pragma unroll
    for (int nf = 0; nf < 2; ++nf) {
        int n = n0 + wn * 64 + nf * 32 + lr;
        bn[nf] = (kz64 == 0) ? bias[n] : 0.f;
    }
#pragma unroll
    for (int mf = 0; mf < 2; ++mf) {
#pragma unroll
        for (int reg = 0; reg < 16; ++reg) {
            int row = (reg & 3) + 8 * (reg >> 2) + 4 * lh;
            int m   = m0 + wm * 64 + mf * 32 + row;
            int bb  = m / 36, pix = m - bb * 36;
            size_t rowp = (size_t)(b_base + bb) * 9216 + pix * 8;
#pragma unroll
            for (int nf = 0; nf < 2; ++nf) {
                int n   = n0 + wn * 64 + nf * 32 + lr;
                int cap = n >> 3, vec = n & 7;
                float v = acc_h[mf][nf][reg]
                        + acc_x[mf][nf][reg] * (1.0f / 2048.0f) + bn[nf];
                atomicAdd(&p[rowp + cap * 288 + vec], v);
            }
        }
    }
}

// ------------------------- dynamic routing (register-priors) ----------------
__global__ void __launch_bounds__(384) routing2(
    const float* __restrict__ p, const float* __restrict__ rw,
    float* __restrict__ caps)
{
    const int b = blockIdx.x;
    const int c = blockIdx.y;
    const int t = threadIdx.x;
    const int lane = t & 63, wid = t >> 6;
    __shared__ float redbuf[6];
    __shared__ float tred[6][16];
    __shared__ float outv[16];

    const float* pb  = p  + (size_t)b * 9216;
    const float* rwc = rw + (size_t)c * 147456;

    float q[3][16];
    float l[3] = {0.f, 0.f, 0.f};

#pragma unroll
    for (int j = 0; j < 3; ++j) {
        int r = t + 384 * j;
        float4 p0 = *(const float4*)&pb[r * 8];
        float4 p1 = *(const float4*)&pb[r * 8 + 4];
        float pr[8] = {p0.x, p0.y, p0.z, p0.w, p1.x, p1.y, p1.z, p1.w};
#pragma unroll
        for (int v = 0; v < 16; ++v) q[j][v] = 0.f;
        const float* wr = rwc + (size_t)r * 128;
#pragma unroll
        for (int i = 0; i < 8; ++i) {
#pragma unroll
            for (int v4 = 0; v4 < 4; ++v4) {
                float4 w4 = *(const float4*)&wr[i * 16 + v4 * 4];
                q[j][v4 * 4 + 0] = fmaf(pr[i], w4.x, q[j][v4 * 4 + 0]);
                q[j][v4 * 4 + 1] = fmaf(pr[i], w4.y, q[j][v4 * 4 + 1]);
                q[j][v4 * 4 + 2] = fmaf(pr[i], w4.z, q[j][v4 * 4 + 2]);
                q[j][v4 * 4 + 3] = fmaf(pr[i], w4.w, q[j][v4 * 4 + 3]);
            }
        }
    }

    for (int it = 0; it < 3; ++it) {
        float lm = fmaxf(fmaxf(l[0], l[1]), l[2]);
#pragma unroll
        for (int off = 32; off; off >>= 1) lm = fmaxf(lm, __shfl_down(lm, off, 64));
        __syncthreads();
        if (lane == 0) redbuf[wid] = lm;
        __syncthreads();
        lm = fmaxf(fmaxf(fmaxf(redbuf[0], redbuf[1]), fmaxf(redbuf[2], redbuf[3])),
                   fmaxf(redbuf[4], redbuf[5]));

        float e[3];
        float ls = 0.f;
#pragma unroll
        for (int j = 0; j < 3; ++j) { e[j] = __expf(l[j] - lm); ls += e[j]; }
#pragma unroll
        for (int off = 32; off; off >>= 1) ls += __shfl_down(ls, off, 64);
        __syncthreads();
        if (lane == 0) redbuf[wid] = ls;
        __syncthreads();
        ls = redbuf[0] + redbuf[1] + redbuf[2] + redbuf[3] + redbuf[4] + redbuf[5];
        const float inv = 1.f / ls;

        float tv[16];
#pragma unroll
        for (int v = 0; v < 16; ++v)
            tv[v] = fmaf(e[0], q[0][v], fmaf(e[1], q[1][v], e[2] * q[2][v]));
#pragma unroll
        for (int v = 0; v < 16; ++v) {
            float xv = tv[v];
#pragma unroll
            for (int off = 32; off; off >>= 1) xv += __shfl_down(xv, off, 64);
            tv[v] = xv;
        }
        __syncthreads();
        if (lane == 0) {
#pragma unroll
            for (int v = 0; v < 16; ++v) tred[wid][v] = tv[v];
        }
        __syncthreads();
        if (t < 16)
            outv[t] = (tred[0][t] + tred[1][t] + tred[2][t]
                     + tred[3][t] + tred[4][t] + tred[5][t]) * inv;
        __syncthreads();

        float s2 = 0.f;
#pragma unroll
        for (int v = 0; v < 16; ++v) s2 += outv[v] * outv[v];
        const float scale = s2 / ((1.f + s2) * sqrtf(s2));

        if (it == 2) {
            if (t < 16) caps[((size_t)b * 2 + c) * 16 + t] = scale * outv[t];
        } else {
            float ov[16];
#pragma unroll
            for (int v = 0; v < 16; ++v) ov[v] = scale * outv[v];
#pragma unroll
            for (int j = 0; j < 3; ++j) {
                float d = 0.f;
#pragma unroll
                for (int v = 0; v < 16; ++v) d = fmaf(q[j][v], ov[v], d);
                l[j] += d;
            }
        }
    }
}

// ------------------------- class softmax + argmax mask ----------------------
__global__ void __launch_bounds__(256) mask_kernel(
    const float* __restrict__ caps, float* __restrict__ cls_out,
    float* __restrict__ masked)
{
    int b = blockIdx.x * 256 + threadIdx.x;
    if (b < 1024) {
        const float* cb = caps + (size_t)b * 32;
        float n0 = 0.f, n1 = 0.f;
#pragma unroll
        for (int v = 0; v < 16; ++v) {
            n0 = fmaf(cb[v], cb[v], n0);
            n1 = fmaf(cb[16 + v], cb[16 + v], n1);
        }
        n0 = sqrtf(n0); n1 = sqrtf(n1);
        float mx = fmaxf(n0, n1);
        float e0 = expf(n0 - mx), e1 = expf(n1 - mx);
        float inv = 1.f / (e0 + e1);
        cls_out[b * 2 + 0] = e0 * inv;
        cls_out[b * 2 + 1] = e1 * inv;
        int cs = (n1 > n0) ? 1 : 0;
#pragma unroll
        for (int v = 0; v < 16; ++v) {
            masked[(size_t)b * 32 + v]      = (cs == 0) ? cb[v] : 0.f;
            masked[(size_t)b * 32 + 16 + v] = (cs == 1) ? cb[16 + v] : 0.f;
        }
    }
}

// ------------------------- decoder GEMM -------------------------------------
template<int ACT>
__global__ void __launch_bounds__(256) dense_gemm(
    const float* __restrict__ A, const float* __restrict__ Bw,
    const float* __restrict__ bias, float* __restrict__ out,
    int M, int N, int K)
{
    __shared__ __align__(16) float As[16][128];
    __shared__ __align__(16) float Bs[16][64];
    const int t  = threadIdx.x;
    const int m0 = blockIdx.x * 128, n0 = blockIdx.y * 64;
    const int tx = t & 15, ty = t >> 4;
    const int am = t >> 1;
    const int ak = (t & 1) * 8;
    const int nb = (t & 15) * 4, kb = t >> 4;

    float acc[8][4];
#pragma unroll
    for (int i = 0; i < 8; ++i)
#pragma unroll
        for (int j = 0; j < 4; ++j) acc[i][j] = 0.f;

    for (int k0i = 0; k0i < K; k0i += 16) {
        {
            const float* ap = A + (size_t)(m0 + am) * K + k0i + ak;
            float4 v0 = *(const float4*)ap;
            float4 v1 = *(const float4*)(ap + 4);
            As[ak + 0][am] = v0.x; As[ak + 1][am] = v0.y;
            As[ak + 2][am] = v0.z; As[ak + 3][am] = v0.w;
            As[ak + 4][am] = v1.x; As[ak + 5][am] = v1.y;
            As[ak + 6][am] = v1.z; As[ak + 7][am] = v1.w;
        }
        {
            int k = k0i + kb;
            int n = n0 + nb;
            float4 v4 = make_float4(0.f, 0.f, 0.f, 0.f);
            if (n + 3 < N) {
                v4 = *(const float4*)&Bw[(size_t)k * N + n];
            } else {
                float tmp[4] = {0.f, 0.f, 0.f, 0.f};
#pragma unroll
                for (int e = 0; e < 4; ++e)
                    if (n + e < N) tmp[e] = Bw[(size_t)k * N + n + e];
                v4 = make_float4(tmp[0], tmp[1], tmp[2], tmp[3]);
            }
            *(float4*)&Bs[kb][nb] = v4;
        }
        __syncthreads();
#pragma unroll
        for (int kk = 0; kk < 16; ++kk) {
            float4 a0 = *(const float4*)&As[kk][ty * 8];
            float4 a1 = *(const float4*)&As[kk][ty * 8 + 4];
            float4 b0 = *(const float4*)&Bs[kk][tx * 4];
            float av[8] = {a0.x, a0.y, a0.z, a0.w, a1.x, a1.y, a1.z, a1.w};
            float bv[4] = {b0.x, b0.y, b0.z, b0.w};
#pragma unroll
            for (int i = 0; i < 8; ++i)
#pragma unroll
                for (int j = 0; j < 4; ++j)
                    acc[i][j] = fmaf(av[i], bv[j], acc[i][j]);
        }
        __syncthreads();
    }
#pragma unroll
    for (int i = 0; i < 8; ++i) {
        int mm = m0 + ty * 8 + i;
#pragma unroll
        for (int j = 0; j < 4; ++j) {
            int n = n0 + tx * 4 + j;
            if (n < N) {
                float v = acc[i][j] + bias[n];
                v = (ACT == 0) ? fmaxf(v, 0.f) : 1.f / (1.f + expf(-v));
                out[(size_t)mm * N + n] = v;
            }
        }
    }
}

// ------------------------- host launcher ------------------------------------
extern "C" void kernel_launch(void* const* d_in, const int* in_sizes, int n_in,
                              void* d_out, int out_size, void* d_ws, size_t ws_size,
                              hipStream_t stream)
{
    const float* x       = (const float*)d_in[0];
    const float* conv1_w = (const float*)d_in[1];
    const float* conv1_b = (const float*)d_in[2];
    const float* prim_w  = (const float*)d_in[3];
    const float* prim_b  = (const float*)d_in[4];
    const float* route_w = (const float*)d_in[5];
    const float* dec_w1  = (const float*)d_in[6];
    const float* dec_b1  = (const float*)d_in[7];
    const float* dec_w2  = (const float*)d_in[8];
    const float* dec_b2  = (const float*)d_in[9];
    const float* dec_w3  = (const float*)d_in[10];
    const float* dec_b3  = (const float*)d_in[11];

    f16*   whT1 = (f16*)d_ws;                       //   65536 halves
    f16*   wlT1 = whT1 + 65536;
    f16*   whT  = wlT1 + 65536;                     // 5308416 halves
    f16*   wlT  = whT + 5308416;
    float* pbuf   = (float*)(wlT + 5308416);        // 9437184 f32
    float* caps   = pbuf + 9437184;
    float* masked = caps + 32768;
    float* d1     = masked + 32768;
    float* d2     = d1 + 524288;
    f16*   hbase  = (f16*)(d2 + 1048576);
    float* outF   = (float*)d_out;

    const size_t fixed_bytes = 65798144ull;
    int chunk = 64;
    const int cand[4] = {512, 256, 128, 64};
    for (int i = 0; i < 4; ++i) {
        if (fixed_bytes + (size_t)cand[i] * 409600ull <= ws_size) {
            chunk = cand[i];
            break;
        }
    }
    f16* hh = hbase;
    f16* hl = hh + (size_t)chunk * 102400;

    // p accumulated via atomics (split-K) -> zero it
    hipMemsetAsync(pbuf, 0, 9437184ull * sizeof(float), stream);

    w1split<<<256, 256, 0, stream>>>(conv1_w, whT1, wlT1);
    transpose_split_w<<<dim3(256, 4), 256, 0, stream>>>(prim_w, whT, wlT);

    const int nchunks = 1024 / chunk;
    for (int ci = 0; ci < nchunks; ++ci) {
        const float* xin = x + (size_t)ci * chunk * 2352;
        conv1_mfma<<<dim3(chunk * 400 / 64, 4), 256, 0, stream>>>(
            xin, whT1, wlT1, conv1_b, hh, hl);
        prim_mfma32<<<dim3(chunk * 36 / 128, 2, 4), 256, 0, stream>>>(
            hh, hl, whT, wlT, prim_b, pbuf, ci * chunk);
    }

    routing2<<<dim3(1024, 2), 384, 0, stream>>>(pbuf, route_w, caps);
    mask_kernel<<<4, 256, 0, stream>>>(caps, outF, masked);

    dense_gemm<0><<<dim3(8, 8),  256, 0, stream>>>(masked, dec_w1, dec_b1, d1, 1024, 512, 32);
    dense_gemm<0><<<dim3(8, 16), 256, 0, stream>>>(d1, dec_w2, dec_b2, d2, 1024, 1024, 512);
    dense_gemm<1><<<dim3(8, 13), 256, 0, stream>>>(d2, dec_w3, dec_b3, outF + 2048, 1024, 784, 1024);
}